// Round 5
// baseline (629.110 us; speedup 1.0000x reference)
//
#include <hip/hip_runtime.h>

#define N_NODES 100000
#define N_EDGES 1600000
#define IN_DIM 64
#define HID 128
#define N_GRAPHS 512
#define NBUCK 391    // ceil(100000/256) buckets of 256 nodes

// ---------------- pass A: per-block LDS histogram of src/dst buckets ----------------
__global__ __launch_bounds__(256) void k_bhist(const int* __restrict__ src, const int* __restrict__ dst,
                                               int* __restrict__ dcnt, int* __restrict__ scnt) {
    __shared__ int hd[NBUCK];
    __shared__ int hs[NBUCK];
    const int t = threadIdx.x;
    const int e0 = blockIdx.x * 4096 + t * 16;
    for (int i = t; i < NBUCK; i += 256) { hd[i] = 0; hs[i] = 0; }
    __syncthreads();
    if (e0 < N_EDGES) {
        const int4* d4 = (const int4*)(dst + e0);
        const int4* s4 = (const int4*)(src + e0);
#pragma unroll
        for (int u = 0; u < 4; ++u) {
            int4 d = d4[u], s = s4[u];
            atomicAdd(&hd[d.x >> 8], 1); atomicAdd(&hd[d.y >> 8], 1);
            atomicAdd(&hd[d.z >> 8], 1); atomicAdd(&hd[d.w >> 8], 1);
            atomicAdd(&hs[s.x >> 8], 1); atomicAdd(&hs[s.y >> 8], 1);
            atomicAdd(&hs[s.z >> 8], 1); atomicAdd(&hs[s.w >> 8], 1);
        }
    }
    __syncthreads();
    for (int i = t; i < NBUCK; i += 256) {
        if (hd[i]) atomicAdd(&dcnt[i], hd[i]);
        if (hs[i]) atomicAdd(&scnt[i], hs[i]);
    }
}

// ---------------- scan bucket counts -> bases + cursors (one block) ----------------
__global__ __launch_bounds__(512) void k_bscan(const int* __restrict__ dcnt, const int* __restrict__ scnt,
                                               int* __restrict__ dbase, int* __restrict__ sbase,
                                               int* __restrict__ dcur, int* __restrict__ scur) {
    __shared__ int l[512];
    const int t = threadIdx.x;
    int v = (t < NBUCK) ? dcnt[t] : 0;
    l[t] = v;
    __syncthreads();
    for (int off = 1; off < 512; off <<= 1) {
        int x = (t >= off) ? l[t - off] : 0;
        __syncthreads();
        l[t] += x;
        __syncthreads();
    }
    if (t < NBUCK) {
        int excl = l[t] - v;
        dbase[t] = excl; dcur[t] = excl;
    }
    if (t == NBUCK - 1) dbase[NBUCK] = l[t];
    __syncthreads();
    v = (t < NBUCK) ? scnt[t] : 0;
    l[t] = v;
    __syncthreads();
    for (int off = 1; off < 512; off <<= 1) {
        int x = (t >= off) ? l[t - off] : 0;
        __syncthreads();
        l[t] += x;
        __syncthreads();
    }
    if (t < NBUCK) {
        int excl = l[t] - v;
        sbase[t] = excl; scur[t] = excl;
    }
    if (t == NBUCK - 1) sbase[NBUCK] = l[t];
}

// ---------------- pass B: bin (src,dst) pairs by dst bucket ----------------
__global__ __launch_bounds__(256) void k_bin_dst(const int* __restrict__ src, const int* __restrict__ dst,
                                                 int* __restrict__ dcur, int2* __restrict__ binned) {
    __shared__ int hist[NBUCK];
    __shared__ int base[NBUCK];
    const int t = threadIdx.x;
    const int e0 = blockIdx.x * 4096 + t * 16;
    for (int i = t; i < NBUCK; i += 256) hist[i] = 0;
    __syncthreads();
    if (e0 < N_EDGES) {
        const int4* d4 = (const int4*)(dst + e0);
#pragma unroll
        for (int u = 0; u < 4; ++u) {
            int4 d = d4[u];
            atomicAdd(&hist[d.x >> 8], 1); atomicAdd(&hist[d.y >> 8], 1);
            atomicAdd(&hist[d.z >> 8], 1); atomicAdd(&hist[d.w >> 8], 1);
        }
    }
    __syncthreads();
    for (int i = t; i < NBUCK; i += 256) {
        int c = hist[i];
        base[i] = c ? atomicAdd(&dcur[i], c) : 0;
        hist[i] = 0;
    }
    __syncthreads();
    if (e0 < N_EDGES) {
        const int4* d4 = (const int4*)(dst + e0);
        const int4* s4 = (const int4*)(src + e0);
#pragma unroll
        for (int u = 0; u < 4; ++u) {
            int4 d = d4[u];
            int4 s = s4[u];
            int bk, r;
            bk = d.x >> 8; r = atomicAdd(&hist[bk], 1); binned[base[bk] + r] = make_int2(s.x, d.x);
            bk = d.y >> 8; r = atomicAdd(&hist[bk], 1); binned[base[bk] + r] = make_int2(s.y, d.y);
            bk = d.z >> 8; r = atomicAdd(&hist[bk], 1); binned[base[bk] + r] = make_int2(s.z, d.z);
            bk = d.w >> 8; r = atomicAdd(&hist[bk], 1); binned[base[bk] + r] = make_int2(s.w, d.w);
        }
    }
}

// ---------------- pass B': bin src ids by src bucket (for out-degree) ----------------
__global__ __launch_bounds__(256) void k_bin_src(const int* __restrict__ src,
                                                 int* __restrict__ scur, int* __restrict__ binnedS) {
    __shared__ int hist[NBUCK];
    __shared__ int base[NBUCK];
    const int t = threadIdx.x;
    const int e0 = blockIdx.x * 4096 + t * 16;
    for (int i = t; i < NBUCK; i += 256) hist[i] = 0;
    __syncthreads();
    if (e0 < N_EDGES) {
        const int4* s4 = (const int4*)(src + e0);
#pragma unroll
        for (int u = 0; u < 4; ++u) {
            int4 s = s4[u];
            atomicAdd(&hist[s.x >> 8], 1); atomicAdd(&hist[s.y >> 8], 1);
            atomicAdd(&hist[s.z >> 8], 1); atomicAdd(&hist[s.w >> 8], 1);
        }
    }
    __syncthreads();
    for (int i = t; i < NBUCK; i += 256) {
        int c = hist[i];
        base[i] = c ? atomicAdd(&scur[i], c) : 0;
        hist[i] = 0;
    }
    __syncthreads();
    if (e0 < N_EDGES) {
        const int4* s4 = (const int4*)(src + e0);
#pragma unroll
        for (int u = 0; u < 4; ++u) {
            int4 s = s4[u];
            int bk, r;
            bk = s.x >> 8; r = atomicAdd(&hist[bk], 1); binnedS[base[bk] + r] = s.x;
            bk = s.y >> 8; r = atomicAdd(&hist[bk], 1); binnedS[base[bk] + r] = s.y;
            bk = s.z >> 8; r = atomicAdd(&hist[bk], 1); binnedS[base[bk] + r] = s.z;
            bk = s.w >> 8; r = atomicAdd(&hist[bk], 1); binnedS[base[bk] + r] = s.w;
        }
    }
}

// ---------------- pass C': per-bucket out-degree count -> rso ----------------
__global__ __launch_bounds__(256) void k_cnt_src(const int* __restrict__ sbase, const int* __restrict__ binnedS,
                                                 float* __restrict__ rso) {
    const int b = blockIdx.x;
    const int n0 = b * 256;
    const int t = threadIdx.x;
    __shared__ int cnt[256];
    __shared__ int sb[2];
    if (t < 2) sb[t] = sbase[b + t];
    cnt[t] = 0;
    __syncthreads();
    const int s = sb[0], e = sb[1];
    for (int i = s + t; i < e; i += 256) atomicAdd(&cnt[binnedS[i] - n0], 1);
    __syncthreads();
    if (n0 + t < N_NODES) rso[n0 + t] = 1.0f / sqrtf(fmaxf((float)cnt[t], 1.0f));
}

// ---------------- pass C: per-bucket in-degree count + scan + CSR scatter ----------------
__global__ __launch_bounds__(256) void k_build_dst(const int* __restrict__ dbase, const int2* __restrict__ binned,
                                                   int* __restrict__ rowp, float* __restrict__ rsi,
                                                   int* __restrict__ col) {
    const int b = blockIdx.x;
    const int n0 = b * 256;
    const int t = threadIdx.x;
    __shared__ int cnt[256];
    __shared__ int scn[256];
    __shared__ int cur[256];
    __shared__ int sb[2];
    if (t < 2) sb[t] = dbase[b + t];
    cnt[t] = 0;
    __syncthreads();
    const int s = sb[0], e = sb[1];
    for (int i = s + t; i < e; i += 256) atomicAdd(&cnt[binned[i].y - n0], 1);
    __syncthreads();
    const int c = cnt[t];
    scn[t] = c;
    __syncthreads();
    for (int off = 1; off < 256; off <<= 1) {
        int v = (t >= off) ? scn[t - off] : 0;
        __syncthreads();
        scn[t] += v;
        __syncthreads();
    }
    const int excl = scn[t] - c;
    cur[t] = excl;
    if (n0 + t < N_NODES) {
        rowp[n0 + t] = s + excl;
        rsi[n0 + t] = 1.0f / sqrtf(fmaxf((float)c, 1.0f));
    }
    if (b == NBUCK - 1 && t == 0) rowp[N_NODES] = e;
    __syncthreads();
    for (int i = s + t; i < e; i += 256) {
        int2 p = binned[i];
        int r = atomicAdd(&cur[p.y - n0], 1);
        col[s + r] = p.x;
    }
}

// ---------------- fused gather + matmul layer ----------------
// Block = 256 threads = 32 dst nodes. Phase 1: 4 waves gather 8 nodes each into
// LDS agg[32][K] (same MLP structure as the standalone gathers). Phase 2: tiled
// f32 matmul from LDS. out[n][j] = relu(agg_dot * rsi[n] + bias[j]) * (SCALE_OUT ? rso[n] : 1)
template <int K, bool GSCALE, bool SCALE_OUT>
__global__ __launch_bounds__(256) void k_gmm(const float4* __restrict__ H4, const float* __restrict__ gsc,
                                             const int* __restrict__ rowp, const int* __restrict__ col,
                                             const float* __restrict__ W, const float* __restrict__ bias,
                                             const float* __restrict__ rsi, const float* __restrict__ rso,
                                             float* __restrict__ out) {
    __shared__ float agg[32][K];
    __shared__ float WL[32 * 128];
    const int t = threadIdx.x;
    const int wid = t >> 6, lane = t & 63;
    const int n0 = blockIdx.x * 32;

    // ---- phase 1: gather 8 nodes per wave ----
#pragma unroll 1
    for (int it = 0; it < 8; ++it) {
        int node = n0 + wid * 8 + it;
        if (node >= N_NODES) continue;
        int s = rowp[node], e = rowp[node + 1];
        if (K == 64) {
            int grp = lane >> 4, li = lane & 15;
            float ax = 0.f, ay = 0.f, az = 0.f, aw = 0.f;
            int i = s + grp;
            for (; i + 12 < e; i += 16) {
                int c0 = col[i], c1 = col[i + 4], c2 = col[i + 8], c3 = col[i + 12];
                float4 v0 = H4[c0 * 16 + li];
                float4 v1 = H4[c1 * 16 + li];
                float4 v2 = H4[c2 * 16 + li];
                float4 v3 = H4[c3 * 16 + li];
                float r0 = GSCALE ? gsc[c0] : 1.f, r1 = GSCALE ? gsc[c1] : 1.f;
                float r2 = GSCALE ? gsc[c2] : 1.f, r3 = GSCALE ? gsc[c3] : 1.f;
                ax = fmaf(r0, v0.x, ax); ay = fmaf(r0, v0.y, ay); az = fmaf(r0, v0.z, az); aw = fmaf(r0, v0.w, aw);
                ax = fmaf(r1, v1.x, ax); ay = fmaf(r1, v1.y, ay); az = fmaf(r1, v1.z, az); aw = fmaf(r1, v1.w, aw);
                ax = fmaf(r2, v2.x, ax); ay = fmaf(r2, v2.y, ay); az = fmaf(r2, v2.z, az); aw = fmaf(r2, v2.w, aw);
                ax = fmaf(r3, v3.x, ax); ay = fmaf(r3, v3.y, ay); az = fmaf(r3, v3.z, az); aw = fmaf(r3, v3.w, aw);
            }
            for (; i < e; i += 4) {
                int c = col[i];
                float4 v = H4[c * 16 + li];
                float r = GSCALE ? gsc[c] : 1.f;
                ax = fmaf(r, v.x, ax); ay = fmaf(r, v.y, ay); az = fmaf(r, v.z, az); aw = fmaf(r, v.w, aw);
            }
            ax += __shfl_xor(ax, 16, 64); ay += __shfl_xor(ay, 16, 64);
            az += __shfl_xor(az, 16, 64); aw += __shfl_xor(aw, 16, 64);
            ax += __shfl_xor(ax, 32, 64); ay += __shfl_xor(ay, 32, 64);
            az += __shfl_xor(az, 32, 64); aw += __shfl_xor(aw, 32, 64);
            if (lane < 16) {
                float4 o; o.x = ax; o.y = ay; o.z = az; o.w = aw;
                ((float4*)agg[node - n0])[li] = o;
            }
        } else {
            int grp = lane >> 5, li = lane & 31;
            float ax = 0.f, ay = 0.f, az = 0.f, aw = 0.f;
            int i = s + grp;
            for (; i + 6 < e; i += 8) {
                int c0 = col[i], c1 = col[i + 2], c2 = col[i + 4], c3 = col[i + 6];
                float4 v0 = H4[c0 * 32 + li];
                float4 v1 = H4[c1 * 32 + li];
                float4 v2 = H4[c2 * 32 + li];
                float4 v3 = H4[c3 * 32 + li];
                ax += v0.x + v1.x + v2.x + v3.x;
                ay += v0.y + v1.y + v2.y + v3.y;
                az += v0.z + v1.z + v2.z + v3.z;
                aw += v0.w + v1.w + v2.w + v3.w;
            }
            for (; i < e; i += 2) {
                float4 v = H4[col[i] * 32 + li];
                ax += v.x; ay += v.y; az += v.z; aw += v.w;
            }
            ax += __shfl_xor(ax, 32, 64); ay += __shfl_xor(ay, 32, 64);
            az += __shfl_xor(az, 32, 64); aw += __shfl_xor(aw, 32, 64);
            if (lane < 32) {
                float4 o; o.x = ax; o.y = ay; o.z = az; o.w = aw;
                ((float4*)agg[node - n0])[li] = o;
            }
        }
    }
    __syncthreads();

    // ---- phase 2: matmul from LDS ----
    const int jq = t & 31;           // columns jq*4 .. jq*4+3
    const int ns = t >> 5;           // nodes ns*4 .. ns*4+3
    float acc[4][4] = {};
    for (int kc = 0; kc < K; kc += 32) {
        const float4* Wg = (const float4*)(W + kc * 128);
        float4* WL4 = (float4*)WL;
#pragma unroll
        for (int u = 0; u < 4; ++u) WL4[t + 256 * u] = Wg[t + 256 * u];
        __syncthreads();
#pragma unroll
        for (int k = 0; k < 32; ++k) {
            float4 wv = ((const float4*)WL)[k * 32 + jq];
#pragma unroll
            for (int i = 0; i < 4; ++i) {
                float av = agg[ns * 4 + i][kc + k];
                acc[i][0] += av * wv.x; acc[i][1] += av * wv.y;
                acc[i][2] += av * wv.z; acc[i][3] += av * wv.w;
            }
        }
        __syncthreads();
    }
#pragma unroll
    for (int i = 0; i < 4; ++i) {
        int node = n0 + ns * 4 + i;
        if (node >= N_NODES) continue;
        float ri = rsi[node];
        float ro = SCALE_OUT ? rso[node] : 1.0f;
        float4 bj = ((const float4*)bias)[jq];
        float4 o;
        o.x = fmaxf(acc[i][0] * ri + bj.x, 0.f) * ro;
        o.y = fmaxf(acc[i][1] * ri + bj.y, 0.f) * ro;
        o.z = fmaxf(acc[i][2] * ri + bj.z, 0.f) * ro;
        o.w = fmaxf(acc[i][3] * ri + bj.w, 0.f) * ro;
        *(float4*)(out + node * HID + jq * 4) = o;
    }
}

// ---------------- per-graph node ranges (graph_ids is sorted) ----------------
__global__ __launch_bounds__(256) void k_bounds(const int* __restrict__ gid, int* __restrict__ gstart) {
    int g = blockIdx.x * 256 + threadIdx.x;
    if (g > N_GRAPHS) return;
    int lo = 0, hi = N_NODES;
    while (lo < hi) {
        int mid = (lo + hi) >> 1;
        if (gid[mid] < g) lo = mid + 1; else hi = mid;
    }
    gstart[g] = lo;
}

// ---------------- mean-pool + 3-layer MLP head, one block per graph ----------------
__global__ __launch_bounds__(128) void k_pool_mlp(const float* __restrict__ h2, const int* __restrict__ gstart,
                                                  const float* __restrict__ Wc1, const float* __restrict__ bc1,
                                                  const float* __restrict__ Wc2, const float* __restrict__ bc2,
                                                  const float* __restrict__ Wc3, const float* __restrict__ bc3,
                                                  float* __restrict__ out) {
    int g = blockIdx.x, t = threadIdx.x;
    int s = gstart[g], e = gstart[g + 1];
    float acc = 0.f;
    for (int n = s; n < e; ++n) acc += h2[n * HID + t];
    float cnt = fmaxf((float)(e - s), 1.0f);
    __shared__ float buf[HID];
    __shared__ float red[2];
    buf[t] = acc / cnt;
    __syncthreads();
    float a = bc1[t];
#pragma unroll 8
    for (int k = 0; k < HID; ++k) a += buf[k] * Wc1[k * HID + t];
    a = fmaxf(a, 0.f);
    __syncthreads();
    buf[t] = a;
    __syncthreads();
    float b = bc2[t];
#pragma unroll 8
    for (int k = 0; k < HID; ++k) b += buf[k] * Wc2[k * HID + t];
    b = fmaxf(b, 0.f);
    float p = b * Wc3[t];
    for (int off = 32; off > 0; off >>= 1) p += __shfl_down(p, off, 64);
    if ((t & 63) == 0) red[t >> 6] = p;
    __syncthreads();
    if (t == 0) out[g] = red[0] + red[1] + bc3[0];
}

extern "C" void kernel_launch(void* const* d_in, const int* in_sizes, int n_in,
                              void* d_out, int out_size, void* d_ws, size_t ws_size,
                              hipStream_t stream) {
    const float* x   = (const float*)d_in[0];
    const int* esrc  = (const int*)d_in[1];
    const int* edst  = (const int*)d_in[2];
    const int* gid   = (const int*)d_in[3];
    const float* W1  = (const float*)d_in[4];
    const float* b1  = (const float*)d_in[5];
    const float* W2  = (const float*)d_in[6];
    const float* b2  = (const float*)d_in[7];
    const float* Wc1 = (const float*)d_in[8];
    const float* bc1 = (const float*)d_in[9];
    const float* Wc2 = (const float*)d_in[10];
    const float* bc2 = (const float*)d_in[11];
    const float* Wc3 = (const float*)d_in[12];
    const float* bc3 = (const float*)d_in[13];
    float* out = (float*)d_out;

    char* w = (char*)d_ws;
    size_t off = 0;
    auto alloc = [&](size_t bytes) -> char* {
        char* p = w + off;
        off += (bytes + 255) & ~(size_t)255;
        return p;
    };
    int* dcnt   = (int*)alloc((size_t)2 * (NBUCK + 1) * 4);  // dcnt+scnt contiguous (one memset)
    int* scnt   = dcnt + (NBUCK + 1);
    int* dbase  = (int*)alloc((size_t)(NBUCK + 1) * 4);
    int* sbase  = (int*)alloc((size_t)(NBUCK + 1) * 4);
    int* dcur   = (int*)alloc((size_t)NBUCK * 4);
    int* scur   = (int*)alloc((size_t)NBUCK * 4);
    float* rso  = (float*)alloc((size_t)N_NODES * 4);
    float* rsi  = (float*)alloc((size_t)N_NODES * 4);
    int* rowp   = (int*)alloc((size_t)(N_NODES + 1) * 4);
    int* gstart = (int*)alloc((size_t)(N_GRAPHS + 1) * 4);
    int* col    = (int*)alloc((size_t)N_EDGES * 4);
    float* R1   = (float*)alloc((size_t)N_NODES * HID * 4);  // binnedD|binnedS, later h2
    float* R2   = (float*)alloc((size_t)N_NODES * HID * 4);  // h1s
    int2* binnedD = (int2*)R1;                         // 12.8 MB
    int*  binnedS = (int*)(R1 + (size_t)N_EDGES * 2);  // 6.4 MB, after binnedD
    float* h1s  = R2;   // layer-1 output (rso folded in)
    float* h2   = R1;   // layer-2 output (binned data dead by then; NOT R2 - gather reads h1s)

    (void)in_sizes; (void)n_in; (void)out_size; (void)ws_size;

    hipMemsetAsync(dcnt, 0, (size_t)2 * (NBUCK + 1) * 4, stream);

    const int BB = (N_EDGES + 4095) / 4096;   // 391 edge blocks
    const int MB = (N_NODES + 31) / 32;       // 3125 fused-layer blocks

    k_bhist<<<BB, 256, 0, stream>>>(esrc, edst, dcnt, scnt);
    k_bscan<<<1, 512, 0, stream>>>(dcnt, scnt, dbase, sbase, dcur, scur);
    k_bin_dst<<<BB, 256, 0, stream>>>(esrc, edst, dcur, binnedD);
    k_bin_src<<<BB, 256, 0, stream>>>(esrc, scur, binnedS);
    k_cnt_src<<<NBUCK, 256, 0, stream>>>(sbase, binnedS, rso);
    k_build_dst<<<NBUCK, 256, 0, stream>>>(dbase, binnedD, rowp, rsi, col);
    k_gmm<IN_DIM, true, true><<<MB, 256, 0, stream>>>((const float4*)x, rso, rowp, col,
                                                      W1, b1, rsi, rso, h1s);
    k_gmm<HID, false, false><<<MB, 256, 0, stream>>>((const float4*)h1s, nullptr, rowp, col,
                                                     W2, b2, rsi, rso, h2);
    k_bounds<<<3, 256, 0, stream>>>(gid, gstart);
    k_pool_mlp<<<N_GRAPHS, 128, 0, stream>>>(h2, gstart, Wc1, bc1, Wc2, bc2, Wc3, bc3, out);
}

// Round 6
// 414.858 us; speedup vs baseline: 1.5164x; 1.5164x over previous
//
#include <hip/hip_runtime.h>

#define N_NODES 100000
#define N_EDGES 1600000
#define IN_DIM 64
#define HID 128
#define N_GRAPHS 512
#define NBUCK 391    // ceil(100000/256) buckets of 256 nodes

// ---------------- pass A: per-block LDS histogram of src/dst buckets ----------------
__global__ __launch_bounds__(256) void k_bhist(const int* __restrict__ src, const int* __restrict__ dst,
                                               int* __restrict__ dcnt, int* __restrict__ scnt) {
    __shared__ int hd[NBUCK];
    __shared__ int hs[NBUCK];
    const int t = threadIdx.x;
    const int e0 = blockIdx.x * 4096 + t * 16;
    for (int i = t; i < NBUCK; i += 256) { hd[i] = 0; hs[i] = 0; }
    __syncthreads();
    if (e0 < N_EDGES) {
        const int4* d4 = (const int4*)(dst + e0);
        const int4* s4 = (const int4*)(src + e0);
#pragma unroll
        for (int u = 0; u < 4; ++u) {
            int4 d = d4[u], s = s4[u];
            atomicAdd(&hd[d.x >> 8], 1); atomicAdd(&hd[d.y >> 8], 1);
            atomicAdd(&hd[d.z >> 8], 1); atomicAdd(&hd[d.w >> 8], 1);
            atomicAdd(&hs[s.x >> 8], 1); atomicAdd(&hs[s.y >> 8], 1);
            atomicAdd(&hs[s.z >> 8], 1); atomicAdd(&hs[s.w >> 8], 1);
        }
    }
    __syncthreads();
    for (int i = t; i < NBUCK; i += 256) {
        if (hd[i]) atomicAdd(&dcnt[i], hd[i]);
        if (hs[i]) atomicAdd(&scnt[i], hs[i]);
    }
}

// ---------------- scan bucket counts -> bases + cursors (one block) ----------------
__global__ __launch_bounds__(512) void k_bscan(const int* __restrict__ dcnt, const int* __restrict__ scnt,
                                               int* __restrict__ dbase, int* __restrict__ sbase,
                                               int* __restrict__ dcur, int* __restrict__ scur) {
    __shared__ int l[512];
    const int t = threadIdx.x;
    int v = (t < NBUCK) ? dcnt[t] : 0;
    l[t] = v;
    __syncthreads();
    for (int off = 1; off < 512; off <<= 1) {
        int x = (t >= off) ? l[t - off] : 0;
        __syncthreads();
        l[t] += x;
        __syncthreads();
    }
    if (t < NBUCK) {
        int excl = l[t] - v;
        dbase[t] = excl; dcur[t] = excl;
    }
    if (t == NBUCK - 1) dbase[NBUCK] = l[t];
    __syncthreads();
    v = (t < NBUCK) ? scnt[t] : 0;
    l[t] = v;
    __syncthreads();
    for (int off = 1; off < 512; off <<= 1) {
        int x = (t >= off) ? l[t - off] : 0;
        __syncthreads();
        l[t] += x;
        __syncthreads();
    }
    if (t < NBUCK) {
        int excl = l[t] - v;
        sbase[t] = excl; scur[t] = excl;
    }
    if (t == NBUCK - 1) sbase[NBUCK] = l[t];
}

// ---------------- pass B: bin (src,dst) pairs by dst bucket ----------------
__global__ __launch_bounds__(256) void k_bin_dst(const int* __restrict__ src, const int* __restrict__ dst,
                                                 int* __restrict__ dcur, int2* __restrict__ binned) {
    __shared__ int hist[NBUCK];
    __shared__ int base[NBUCK];
    const int t = threadIdx.x;
    const int e0 = blockIdx.x * 4096 + t * 16;
    for (int i = t; i < NBUCK; i += 256) hist[i] = 0;
    __syncthreads();
    if (e0 < N_EDGES) {
        const int4* d4 = (const int4*)(dst + e0);
#pragma unroll
        for (int u = 0; u < 4; ++u) {
            int4 d = d4[u];
            atomicAdd(&hist[d.x >> 8], 1); atomicAdd(&hist[d.y >> 8], 1);
            atomicAdd(&hist[d.z >> 8], 1); atomicAdd(&hist[d.w >> 8], 1);
        }
    }
    __syncthreads();
    for (int i = t; i < NBUCK; i += 256) {
        int c = hist[i];
        base[i] = c ? atomicAdd(&dcur[i], c) : 0;
        hist[i] = 0;
    }
    __syncthreads();
    if (e0 < N_EDGES) {
        const int4* d4 = (const int4*)(dst + e0);
        const int4* s4 = (const int4*)(src + e0);
#pragma unroll
        for (int u = 0; u < 4; ++u) {
            int4 d = d4[u];
            int4 s = s4[u];
            int bk, r;
            bk = d.x >> 8; r = atomicAdd(&hist[bk], 1); binned[base[bk] + r] = make_int2(s.x, d.x);
            bk = d.y >> 8; r = atomicAdd(&hist[bk], 1); binned[base[bk] + r] = make_int2(s.y, d.y);
            bk = d.z >> 8; r = atomicAdd(&hist[bk], 1); binned[base[bk] + r] = make_int2(s.z, d.z);
            bk = d.w >> 8; r = atomicAdd(&hist[bk], 1); binned[base[bk] + r] = make_int2(s.w, d.w);
        }
    }
}

// ---------------- pass B': bin src ids by src bucket (for out-degree) ----------------
__global__ __launch_bounds__(256) void k_bin_src(const int* __restrict__ src,
                                                 int* __restrict__ scur, int* __restrict__ binnedS) {
    __shared__ int hist[NBUCK];
    __shared__ int base[NBUCK];
    const int t = threadIdx.x;
    const int e0 = blockIdx.x * 4096 + t * 16;
    for (int i = t; i < NBUCK; i += 256) hist[i] = 0;
    __syncthreads();
    if (e0 < N_EDGES) {
        const int4* s4 = (const int4*)(src + e0);
#pragma unroll
        for (int u = 0; u < 4; ++u) {
            int4 s = s4[u];
            atomicAdd(&hist[s.x >> 8], 1); atomicAdd(&hist[s.y >> 8], 1);
            atomicAdd(&hist[s.z >> 8], 1); atomicAdd(&hist[s.w >> 8], 1);
        }
    }
    __syncthreads();
    for (int i = t; i < NBUCK; i += 256) {
        int c = hist[i];
        base[i] = c ? atomicAdd(&scur[i], c) : 0;
        hist[i] = 0;
    }
    __syncthreads();
    if (e0 < N_EDGES) {
        const int4* s4 = (const int4*)(src + e0);
#pragma unroll
        for (int u = 0; u < 4; ++u) {
            int4 s = s4[u];
            int bk, r;
            bk = s.x >> 8; r = atomicAdd(&hist[bk], 1); binnedS[base[bk] + r] = s.x;
            bk = s.y >> 8; r = atomicAdd(&hist[bk], 1); binnedS[base[bk] + r] = s.y;
            bk = s.z >> 8; r = atomicAdd(&hist[bk], 1); binnedS[base[bk] + r] = s.z;
            bk = s.w >> 8; r = atomicAdd(&hist[bk], 1); binnedS[base[bk] + r] = s.w;
        }
    }
}

// ---------------- pass C': per-bucket out-degree count -> rso ----------------
__global__ __launch_bounds__(256) void k_cnt_src(const int* __restrict__ sbase, const int* __restrict__ binnedS,
                                                 float* __restrict__ rso) {
    const int b = blockIdx.x;
    const int n0 = b * 256;
    const int t = threadIdx.x;
    __shared__ int cnt[256];
    __shared__ int sb[2];
    if (t < 2) sb[t] = sbase[b + t];
    cnt[t] = 0;
    __syncthreads();
    const int s = sb[0], e = sb[1];
    for (int i = s + t; i < e; i += 256) atomicAdd(&cnt[binnedS[i] - n0], 1);
    __syncthreads();
    if (n0 + t < N_NODES) rso[n0 + t] = 1.0f / sqrtf(fmaxf((float)cnt[t], 1.0f));
}

// ---------------- pass C: per-bucket in-degree count + scan + CSR scatter ----------------
__global__ __launch_bounds__(256) void k_build_dst(const int* __restrict__ dbase, const int2* __restrict__ binned,
                                                   int* __restrict__ rowp, float* __restrict__ rsi,
                                                   int* __restrict__ col) {
    const int b = blockIdx.x;
    const int n0 = b * 256;
    const int t = threadIdx.x;
    __shared__ int cnt[256];
    __shared__ int scn[256];
    __shared__ int cur[256];
    __shared__ int sb[2];
    if (t < 2) sb[t] = dbase[b + t];
    cnt[t] = 0;
    __syncthreads();
    const int s = sb[0], e = sb[1];
    for (int i = s + t; i < e; i += 256) atomicAdd(&cnt[binned[i].y - n0], 1);
    __syncthreads();
    const int c = cnt[t];
    scn[t] = c;
    __syncthreads();
    for (int off = 1; off < 256; off <<= 1) {
        int v = (t >= off) ? scn[t - off] : 0;
        __syncthreads();
        scn[t] += v;
        __syncthreads();
    }
    const int excl = scn[t] - c;
    cur[t] = excl;
    if (n0 + t < N_NODES) {
        rowp[n0 + t] = s + excl;
        rsi[n0 + t] = 1.0f / sqrtf(fmaxf((float)c, 1.0f));
    }
    if (b == NBUCK - 1 && t == 0) rowp[N_NODES] = e;
    __syncthreads();
    for (int i = s + t; i < e; i += 256) {
        int2 p = binned[i];
        int r = atomicAdd(&cur[p.y - n0], 1);
        col[s + r] = p.x;
    }
}

// ---------------- gather-sum aggregation (64-dim), rso scale fused ----------------
// 4 groups of 16 lanes, float4/lane; 4-unroll main + 2-unroll mid + tail.
__global__ __launch_bounds__(256) void k_gather64(const float4* __restrict__ x4, const float* __restrict__ rso,
                                                  const int* __restrict__ rowp, const int* __restrict__ col,
                                                  float4* __restrict__ agg4) {
    int wv = (blockIdx.x * 256 + threadIdx.x) >> 6;
    if (wv >= N_NODES) return;
    int lane = threadIdx.x & 63;
    int grp = lane >> 4, li = lane & 15;
    int s = rowp[wv], e = rowp[wv + 1];
    float ax = 0.f, ay = 0.f, az = 0.f, aw = 0.f;
    int i = s + grp;
    for (; i + 12 < e; i += 16) {
        int c0 = col[i], c1 = col[i + 4], c2 = col[i + 8], c3 = col[i + 12];
        float4 v0 = x4[c0 * 16 + li];
        float4 v1 = x4[c1 * 16 + li];
        float4 v2 = x4[c2 * 16 + li];
        float4 v3 = x4[c3 * 16 + li];
        float r0 = rso[c0], r1 = rso[c1], r2 = rso[c2], r3 = rso[c3];
        ax = fmaf(r0, v0.x, ax); ay = fmaf(r0, v0.y, ay); az = fmaf(r0, v0.z, az); aw = fmaf(r0, v0.w, aw);
        ax = fmaf(r1, v1.x, ax); ay = fmaf(r1, v1.y, ay); az = fmaf(r1, v1.z, az); aw = fmaf(r1, v1.w, aw);
        ax = fmaf(r2, v2.x, ax); ay = fmaf(r2, v2.y, ay); az = fmaf(r2, v2.z, az); aw = fmaf(r2, v2.w, aw);
        ax = fmaf(r3, v3.x, ax); ay = fmaf(r3, v3.y, ay); az = fmaf(r3, v3.z, az); aw = fmaf(r3, v3.w, aw);
    }
    for (; i + 4 < e; i += 8) {
        int c0 = col[i], c1 = col[i + 4];
        float4 v0 = x4[c0 * 16 + li];
        float4 v1 = x4[c1 * 16 + li];
        float r0 = rso[c0], r1 = rso[c1];
        ax = fmaf(r0, v0.x, ax); ay = fmaf(r0, v0.y, ay); az = fmaf(r0, v0.z, az); aw = fmaf(r0, v0.w, aw);
        ax = fmaf(r1, v1.x, ax); ay = fmaf(r1, v1.y, ay); az = fmaf(r1, v1.z, az); aw = fmaf(r1, v1.w, aw);
    }
    for (; i < e; i += 4) {
        int c = col[i];
        float4 v = x4[c * 16 + li];
        float r = rso[c];
        ax = fmaf(r, v.x, ax); ay = fmaf(r, v.y, ay); az = fmaf(r, v.z, az); aw = fmaf(r, v.w, aw);
    }
    ax += __shfl_xor(ax, 16, 64); ay += __shfl_xor(ay, 16, 64);
    az += __shfl_xor(az, 16, 64); aw += __shfl_xor(aw, 16, 64);
    ax += __shfl_xor(ax, 32, 64); ay += __shfl_xor(ay, 32, 64);
    az += __shfl_xor(az, 32, 64); aw += __shfl_xor(aw, 32, 64);
    if (lane < 16) {
        float4 o; o.x = ax; o.y = ay; o.z = az; o.w = aw;
        agg4[wv * 16 + li] = o;
    }
}

// ---------------- gather-sum aggregation (128-dim) ----------------
// 2 groups of 32 lanes, float4/lane; 8-unroll main (16 rows in flight/wave) + 4 + tail.
__global__ __launch_bounds__(256) void k_gather128(const float4* __restrict__ h4, const int* __restrict__ rowp,
                                                   const int* __restrict__ col, float4* __restrict__ agg4) {
    int wv = (blockIdx.x * 256 + threadIdx.x) >> 6;
    if (wv >= N_NODES) return;
    int lane = threadIdx.x & 63;
    int grp = lane >> 5, li = lane & 31;
    int s = rowp[wv], e = rowp[wv + 1];
    float ax = 0.f, ay = 0.f, az = 0.f, aw = 0.f;
    int i = s + grp;
    for (; i + 14 < e; i += 16) {
        int c0 = col[i],      c1 = col[i + 2],  c2 = col[i + 4],  c3 = col[i + 6];
        int c4 = col[i + 8],  c5 = col[i + 10], c6 = col[i + 12], c7 = col[i + 14];
        float4 v0 = h4[c0 * 32 + li];
        float4 v1 = h4[c1 * 32 + li];
        float4 v2 = h4[c2 * 32 + li];
        float4 v3 = h4[c3 * 32 + li];
        float4 v4 = h4[c4 * 32 + li];
        float4 v5 = h4[c5 * 32 + li];
        float4 v6 = h4[c6 * 32 + li];
        float4 v7 = h4[c7 * 32 + li];
        ax += (v0.x + v1.x) + (v2.x + v3.x) + ((v4.x + v5.x) + (v6.x + v7.x));
        ay += (v0.y + v1.y) + (v2.y + v3.y) + ((v4.y + v5.y) + (v6.y + v7.y));
        az += (v0.z + v1.z) + (v2.z + v3.z) + ((v4.z + v5.z) + (v6.z + v7.z));
        aw += (v0.w + v1.w) + (v2.w + v3.w) + ((v4.w + v5.w) + (v6.w + v7.w));
    }
    for (; i + 6 < e; i += 8) {
        int c0 = col[i], c1 = col[i + 2], c2 = col[i + 4], c3 = col[i + 6];
        float4 v0 = h4[c0 * 32 + li];
        float4 v1 = h4[c1 * 32 + li];
        float4 v2 = h4[c2 * 32 + li];
        float4 v3 = h4[c3 * 32 + li];
        ax += v0.x + v1.x + v2.x + v3.x;
        ay += v0.y + v1.y + v2.y + v3.y;
        az += v0.z + v1.z + v2.z + v3.z;
        aw += v0.w + v1.w + v2.w + v3.w;
    }
    for (; i < e; i += 2) {
        float4 v = h4[col[i] * 32 + li];
        ax += v.x; ay += v.y; az += v.z; aw += v.w;
    }
    ax += __shfl_xor(ax, 32, 64); ay += __shfl_xor(ay, 32, 64);
    az += __shfl_xor(az, 32, 64); aw += __shfl_xor(aw, 32, 64);
    if (lane < 32) {
        float4 o; o.x = ax; o.y = ay; o.z = az; o.w = aw;
        agg4[wv * 32 + li] = o;
    }
}

// ---------------- tiled f32 matmul, 64-node tile: out = epilogue(A @ W) ----------------
// A: [n, K], W: [K, 128]. Per thread: 8 nodes x 4 cols (acc[8][4]) -> 32 FMA per
// 9 LDS ops (8 conflict-free broadcasts + 1 b128). VALU-bound.
template <int K, bool SCALE_OUT>
__global__ __launch_bounds__(256) void k_mm(const float* __restrict__ A, const float* __restrict__ W,
                                            const float* __restrict__ bias, const float* __restrict__ rsi,
                                            const float* __restrict__ rso, float* __restrict__ out) {
    __shared__ float WL[32 * 128];   // one 32-row chunk of W (16 KB)
    __shared__ float aL[64][33];     // 64 nodes x 32 k (padded, 8.4 KB)
    const int t = threadIdx.x;
    const int jq = t & 31;           // columns jq*4 .. jq*4+3
    const int ns = t >> 5;           // node group: nodes ns*8 .. ns*8+7
    const int n0 = blockIdx.x * 64;
    float acc[8][4] = {};
    for (int kc = 0; kc < K; kc += 32) {
        const float4* Wg = (const float4*)(W + kc * 128);
        float4* WL4 = (float4*)WL;
#pragma unroll
        for (int u = 0; u < 4; ++u) WL4[t + 256 * u] = Wg[t + 256 * u];
        {
            int r = t >> 2, q = t & 3;   // node row r (0..63), quad q
            int node = n0 + r;
#pragma unroll
            for (int h = 0; h < 2; ++h) {
                int qq = q + h * 4;      // k-quad 0..7
                float4 v = make_float4(0.f, 0.f, 0.f, 0.f);
                if (node < N_NODES) v = *(const float4*)(A + (size_t)node * K + kc + qq * 4);
                aL[r][qq * 4 + 0] = v.x; aL[r][qq * 4 + 1] = v.y;
                aL[r][qq * 4 + 2] = v.z; aL[r][qq * 4 + 3] = v.w;
            }
        }
        __syncthreads();
#pragma unroll
        for (int k = 0; k < 32; ++k) {
            float4 wv = ((const float4*)WL)[k * 32 + jq];
#pragma unroll
            for (int i = 0; i < 8; ++i) {
                float av = aL[ns * 8 + i][k];
                acc[i][0] += av * wv.x; acc[i][1] += av * wv.y;
                acc[i][2] += av * wv.z; acc[i][3] += av * wv.w;
            }
        }
        __syncthreads();
    }
#pragma unroll
    for (int i = 0; i < 8; ++i) {
        int node = n0 + ns * 8 + i;
        if (node >= N_NODES) continue;
        float ri = rsi[node];
        float ro = SCALE_OUT ? rso[node] : 1.0f;
        float4 bj = ((const float4*)bias)[jq];
        float4 o;
        o.x = fmaxf(acc[i][0] * ri + bj.x, 0.f) * ro;
        o.y = fmaxf(acc[i][1] * ri + bj.y, 0.f) * ro;
        o.z = fmaxf(acc[i][2] * ri + bj.z, 0.f) * ro;
        o.w = fmaxf(acc[i][3] * ri + bj.w, 0.f) * ro;
        *(float4*)(out + node * HID + jq * 4) = o;
    }
}

// ---------------- per-graph node ranges (graph_ids is sorted) ----------------
__global__ __launch_bounds__(256) void k_bounds(const int* __restrict__ gid, int* __restrict__ gstart) {
    int g = blockIdx.x * 256 + threadIdx.x;
    if (g > N_GRAPHS) return;
    int lo = 0, hi = N_NODES;
    while (lo < hi) {
        int mid = (lo + hi) >> 1;
        if (gid[mid] < g) lo = mid + 1; else hi = mid;
    }
    gstart[g] = lo;
}

// ---------------- mean-pool + 3-layer MLP head, one block per graph ----------------
__global__ __launch_bounds__(128) void k_pool_mlp(const float* __restrict__ h2, const int* __restrict__ gstart,
                                                  const float* __restrict__ Wc1, const float* __restrict__ bc1,
                                                  const float* __restrict__ Wc2, const float* __restrict__ bc2,
                                                  const float* __restrict__ Wc3, const float* __restrict__ bc3,
                                                  float* __restrict__ out) {
    int g = blockIdx.x, t = threadIdx.x;
    int s = gstart[g], e = gstart[g + 1];
    float acc = 0.f;
    for (int n = s; n < e; ++n) acc += h2[n * HID + t];
    float cnt = fmaxf((float)(e - s), 1.0f);
    __shared__ float buf[HID];
    __shared__ float red[2];
    buf[t] = acc / cnt;
    __syncthreads();
    float a = bc1[t];
#pragma unroll 8
    for (int k = 0; k < HID; ++k) a += buf[k] * Wc1[k * HID + t];
    a = fmaxf(a, 0.f);
    __syncthreads();
    buf[t] = a;
    __syncthreads();
    float b = bc2[t];
#pragma unroll 8
    for (int k = 0; k < HID; ++k) b += buf[k] * Wc2[k * HID + t];
    b = fmaxf(b, 0.f);
    float p = b * Wc3[t];
    for (int off = 32; off > 0; off >>= 1) p += __shfl_down(p, off, 64);
    if ((t & 63) == 0) red[t >> 6] = p;
    __syncthreads();
    if (t == 0) out[g] = red[0] + red[1] + bc3[0];
}

extern "C" void kernel_launch(void* const* d_in, const int* in_sizes, int n_in,
                              void* d_out, int out_size, void* d_ws, size_t ws_size,
                              hipStream_t stream) {
    const float* x   = (const float*)d_in[0];
    const int* esrc  = (const int*)d_in[1];
    const int* edst  = (const int*)d_in[2];
    const int* gid   = (const int*)d_in[3];
    const float* W1  = (const float*)d_in[4];
    const float* b1  = (const float*)d_in[5];
    const float* W2  = (const float*)d_in[6];
    const float* b2  = (const float*)d_in[7];
    const float* Wc1 = (const float*)d_in[8];
    const float* bc1 = (const float*)d_in[9];
    const float* Wc2 = (const float*)d_in[10];
    const float* bc2 = (const float*)d_in[11];
    const float* Wc3 = (const float*)d_in[12];
    const float* bc3 = (const float*)d_in[13];
    float* out = (float*)d_out;

    char* w = (char*)d_ws;
    size_t off = 0;
    auto alloc = [&](size_t bytes) -> char* {
        char* p = w + off;
        off += (bytes + 255) & ~(size_t)255;
        return p;
    };
    int* dcnt   = (int*)alloc((size_t)2 * (NBUCK + 1) * 4);  // dcnt+scnt contiguous (one memset)
    int* scnt   = dcnt + (NBUCK + 1);
    int* dbase  = (int*)alloc((size_t)(NBUCK + 1) * 4);
    int* sbase  = (int*)alloc((size_t)(NBUCK + 1) * 4);
    int* dcur   = (int*)alloc((size_t)NBUCK * 4);
    int* scur   = (int*)alloc((size_t)NBUCK * 4);
    float* rso  = (float*)alloc((size_t)N_NODES * 4);
    float* rsi  = (float*)alloc((size_t)N_NODES * 4);
    int* rowp   = (int*)alloc((size_t)(N_NODES + 1) * 4);
    int* gstart = (int*)alloc((size_t)(N_GRAPHS + 1) * 4);
    int* col    = (int*)alloc((size_t)N_EDGES * 4);
    float* R1   = (float*)alloc((size_t)N_NODES * HID * 4);  // binnedD | binnedS | agg1 | agg2
    float* R2   = (float*)alloc((size_t)N_NODES * HID * 4);  // h1s, later h2
    int2* binnedD = (int2*)R1;                         // 12.8 MB
    int*  binnedS = (int*)(R1 + (size_t)N_EDGES * 2);  // 6.4 MB, after binnedD
    float* agg1 = R1;
    float* agg2 = R1;
    float* h1s  = R2;
    float* h2   = R2;

    (void)in_sizes; (void)n_in; (void)out_size; (void)ws_size;

    hipMemsetAsync(dcnt, 0, (size_t)2 * (NBUCK + 1) * 4, stream);

    const int BB = (N_EDGES + 4095) / 4096;     // 391 edge blocks
    const int GB = (N_NODES * 64 + 255) / 256;  // one wave per node
    const int MB64 = (N_NODES + 63) / 64;       // 1563 matmul blocks

    k_bhist<<<BB, 256, 0, stream>>>(esrc, edst, dcnt, scnt);
    k_bscan<<<1, 512, 0, stream>>>(dcnt, scnt, dbase, sbase, dcur, scur);
    k_bin_dst<<<BB, 256, 0, stream>>>(esrc, edst, dcur, binnedD);
    k_bin_src<<<BB, 256, 0, stream>>>(esrc, scur, binnedS);
    k_cnt_src<<<NBUCK, 256, 0, stream>>>(sbase, binnedS, rso);
    k_build_dst<<<NBUCK, 256, 0, stream>>>(dbase, binnedD, rowp, rsi, col);
    k_gather64<<<GB, 256, 0, stream>>>((const float4*)x, rso, rowp, col, (float4*)agg1);
    k_mm<IN_DIM, true><<<MB64, 256, 0, stream>>>(agg1, W1, b1, rsi, rso, h1s);
    k_gather128<<<GB, 256, 0, stream>>>((const float4*)h1s, rowp, col, (float4*)agg2);
    k_mm<HID, false><<<MB64, 256, 0, stream>>>(agg2, W2, b2, rsi, rso, h2);
    k_bounds<<<3, 256, 0, stream>>>(gid, gstart);
    k_pool_mlp<<<N_GRAPHS, 128, 0, stream>>>(h2, gstart, Wc1, bc1, Wc2, bc2, Wc3, bc3, out);
}

// Round 7
// 350.053 us; speedup vs baseline: 1.7972x; 1.1851x over previous
//
#include <hip/hip_runtime.h>

#define N_NODES 100000
#define N_EDGES 1600000
#define IN_DIM 64
#define HID 128
#define N_GRAPHS 512
#define NBUCK 391    // ceil(100000/256) buckets of 256 nodes

// ---------------- pass A: per-block LDS histogram of src/dst buckets ----------------
__global__ __launch_bounds__(256) void k_bhist(const int* __restrict__ src, const int* __restrict__ dst,
                                               int* __restrict__ dcnt, int* __restrict__ scnt) {
    __shared__ int hd[NBUCK];
    __shared__ int hs[NBUCK];
    const int t = threadIdx.x;
    const int e0 = blockIdx.x * 4096 + t * 16;
    for (int i = t; i < NBUCK; i += 256) { hd[i] = 0; hs[i] = 0; }
    __syncthreads();
    if (e0 < N_EDGES) {
        const int4* d4 = (const int4*)(dst + e0);
        const int4* s4 = (const int4*)(src + e0);
#pragma unroll
        for (int u = 0; u < 4; ++u) {
            int4 d = d4[u], s = s4[u];
            atomicAdd(&hd[d.x >> 8], 1); atomicAdd(&hd[d.y >> 8], 1);
            atomicAdd(&hd[d.z >> 8], 1); atomicAdd(&hd[d.w >> 8], 1);
            atomicAdd(&hs[s.x >> 8], 1); atomicAdd(&hs[s.y >> 8], 1);
            atomicAdd(&hs[s.z >> 8], 1); atomicAdd(&hs[s.w >> 8], 1);
        }
    }
    __syncthreads();
    for (int i = t; i < NBUCK; i += 256) {
        if (hd[i]) atomicAdd(&dcnt[i], hd[i]);
        if (hs[i]) atomicAdd(&scnt[i], hs[i]);
    }
}

// ---------------- scans (blocks 0,1) + per-graph bounds (block 2) ----------------
__global__ __launch_bounds__(512) void k_bscan3(const int* __restrict__ dcnt, const int* __restrict__ scnt,
                                                const int* __restrict__ gid,
                                                int* __restrict__ dbase, int* __restrict__ sbase,
                                                int* __restrict__ dcur, int* __restrict__ scur,
                                                int* __restrict__ gstart) {
    const int t = threadIdx.x;
    if (blockIdx.x == 2) {
        for (int g = t; g <= N_GRAPHS; g += 512) {
            int lo = 0, hi = N_NODES;
            while (lo < hi) {
                int mid = (lo + hi) >> 1;
                if (gid[mid] < g) lo = mid + 1; else hi = mid;
            }
            gstart[g] = lo;
        }
        return;
    }
    __shared__ int l[512];
    const int* cntp = (blockIdx.x == 0) ? dcnt : scnt;
    int* basep = (blockIdx.x == 0) ? dbase : sbase;
    int* curp  = (blockIdx.x == 0) ? dcur  : scur;
    int v = (t < NBUCK) ? cntp[t] : 0;
    l[t] = v;
    __syncthreads();
    for (int off = 1; off < 512; off <<= 1) {
        int x = (t >= off) ? l[t - off] : 0;
        __syncthreads();
        l[t] += x;
        __syncthreads();
    }
    if (t < NBUCK) {
        int excl = l[t] - v;
        basep[t] = excl; curp[t] = excl;
    }
    if (t == NBUCK - 1) basep[NBUCK] = l[t];
}

// ---------------- pass B: bin by dst bucket (packed src|dstLocal) AND by src bucket ----------------
__global__ __launch_bounds__(256) void k_bin2(const int* __restrict__ src, const int* __restrict__ dst,
                                              int* __restrict__ dcur, int* __restrict__ scur,
                                              int* __restrict__ binnedD, int* __restrict__ binnedS) {
    __shared__ int hd[NBUCK];
    __shared__ int bd[NBUCK];
    __shared__ int hs[NBUCK];
    __shared__ int bs[NBUCK];
    const int t = threadIdx.x;
    const int e0 = blockIdx.x * 4096 + t * 16;
    for (int i = t; i < NBUCK; i += 256) { hd[i] = 0; hs[i] = 0; }
    __syncthreads();
    if (e0 < N_EDGES) {
        const int4* d4 = (const int4*)(dst + e0);
        const int4* s4 = (const int4*)(src + e0);
#pragma unroll
        for (int u = 0; u < 4; ++u) {
            int4 d = d4[u], s = s4[u];
            atomicAdd(&hd[d.x >> 8], 1); atomicAdd(&hd[d.y >> 8], 1);
            atomicAdd(&hd[d.z >> 8], 1); atomicAdd(&hd[d.w >> 8], 1);
            atomicAdd(&hs[s.x >> 8], 1); atomicAdd(&hs[s.y >> 8], 1);
            atomicAdd(&hs[s.z >> 8], 1); atomicAdd(&hs[s.w >> 8], 1);
        }
    }
    __syncthreads();
    for (int i = t; i < NBUCK; i += 256) {
        int c = hd[i];
        bd[i] = c ? atomicAdd(&dcur[i], c) : 0;
        hd[i] = 0;
        c = hs[i];
        bs[i] = c ? atomicAdd(&scur[i], c) : 0;
        hs[i] = 0;
    }
    __syncthreads();
    if (e0 < N_EDGES) {
        const int4* d4 = (const int4*)(dst + e0);
        const int4* s4 = (const int4*)(src + e0);
#pragma unroll
        for (int u = 0; u < 4; ++u) {
            int4 d = d4[u];
            int4 s = s4[u];
            int bk, r;
            bk = d.x >> 8; r = atomicAdd(&hd[bk], 1); binnedD[bd[bk] + r] = s.x | ((d.x & 255) << 17);
            bk = d.y >> 8; r = atomicAdd(&hd[bk], 1); binnedD[bd[bk] + r] = s.y | ((d.y & 255) << 17);
            bk = d.z >> 8; r = atomicAdd(&hd[bk], 1); binnedD[bd[bk] + r] = s.z | ((d.z & 255) << 17);
            bk = d.w >> 8; r = atomicAdd(&hd[bk], 1); binnedD[bd[bk] + r] = s.w | ((d.w & 255) << 17);
            bk = s.x >> 8; r = atomicAdd(&hs[bk], 1); binnedS[bs[bk] + r] = s.x;
            bk = s.y >> 8; r = atomicAdd(&hs[bk], 1); binnedS[bs[bk] + r] = s.y;
            bk = s.z >> 8; r = atomicAdd(&hs[bk], 1); binnedS[bs[bk] + r] = s.z;
            bk = s.w >> 8; r = atomicAdd(&hs[bk], 1); binnedS[bs[bk] + r] = s.w;
        }
    }
}

// ---------------- pass C: CSR build (blocks 0..NBUCK-1) + out-degree rso (blocks NBUCK..) ----------------
__global__ __launch_bounds__(256) void k_prep2(const int* __restrict__ dbase, const int* __restrict__ sbase,
                                               const int* __restrict__ binnedD, const int* __restrict__ binnedS,
                                               int* __restrict__ rowp, float* __restrict__ rsi,
                                               float* __restrict__ rso, int* __restrict__ col) {
    const int t = threadIdx.x;
    if (blockIdx.x < NBUCK) {
        const int b = blockIdx.x;
        const int n0 = b * 256;
        __shared__ int cnt[256];
        __shared__ int scn[256];
        __shared__ int cur[256];
        __shared__ int sb[2];
        if (t < 2) sb[t] = dbase[b + t];
        cnt[t] = 0;
        __syncthreads();
        const int s = sb[0], e = sb[1];
        for (int i = s + t; i < e; i += 256) atomicAdd(&cnt[binnedD[i] >> 17], 1);
        __syncthreads();
        const int c = cnt[t];
        scn[t] = c;
        __syncthreads();
        for (int off = 1; off < 256; off <<= 1) {
            int v = (t >= off) ? scn[t - off] : 0;
            __syncthreads();
            scn[t] += v;
            __syncthreads();
        }
        const int excl = scn[t] - c;
        cur[t] = excl;
        if (n0 + t < N_NODES) {
            rowp[n0 + t] = s + excl;
            rsi[n0 + t] = 1.0f / sqrtf(fmaxf((float)c, 1.0f));
        }
        if (b == NBUCK - 1 && t == 0) rowp[N_NODES] = e;
        __syncthreads();
        for (int i = s + t; i < e; i += 256) {
            int p = binnedD[i];
            int r = atomicAdd(&cur[p >> 17], 1);
            col[s + r] = p & 0x1FFFF;
        }
    } else {
        const int b = blockIdx.x - NBUCK;
        const int n0 = b * 256;
        __shared__ int cnt2[256];
        __shared__ int sb2[2];
        if (t < 2) sb2[t] = sbase[b + t];
        cnt2[t] = 0;
        __syncthreads();
        const int s = sb2[0], e = sb2[1];
        for (int i = s + t; i < e; i += 256) atomicAdd(&cnt2[binnedS[i] - n0], 1);
        __syncthreads();
        if (n0 + t < N_NODES) rso[n0 + t] = 1.0f / sqrtf(fmaxf((float)cnt2[t], 1.0f));
    }
}

// ---------------- gather-sum aggregation (64-dim), rso scale fused ----------------
__global__ __launch_bounds__(256) void k_gather64(const float4* __restrict__ x4, const float* __restrict__ rso,
                                                  const int* __restrict__ rowp, const int* __restrict__ col,
                                                  float4* __restrict__ agg4) {
    int wv = (blockIdx.x * 256 + threadIdx.x) >> 6;
    if (wv >= N_NODES) return;
    int lane = threadIdx.x & 63;
    int grp = lane >> 4, li = lane & 15;
    int s = rowp[wv], e = rowp[wv + 1];
    float ax = 0.f, ay = 0.f, az = 0.f, aw = 0.f;
    int i = s + grp;
    for (; i + 12 < e; i += 16) {
        int c0 = col[i], c1 = col[i + 4], c2 = col[i + 8], c3 = col[i + 12];
        float4 v0 = x4[c0 * 16 + li];
        float4 v1 = x4[c1 * 16 + li];
        float4 v2 = x4[c2 * 16 + li];
        float4 v3 = x4[c3 * 16 + li];
        float r0 = rso[c0], r1 = rso[c1], r2 = rso[c2], r3 = rso[c3];
        ax = fmaf(r0, v0.x, ax); ay = fmaf(r0, v0.y, ay); az = fmaf(r0, v0.z, az); aw = fmaf(r0, v0.w, aw);
        ax = fmaf(r1, v1.x, ax); ay = fmaf(r1, v1.y, ay); az = fmaf(r1, v1.z, az); aw = fmaf(r1, v1.w, aw);
        ax = fmaf(r2, v2.x, ax); ay = fmaf(r2, v2.y, ay); az = fmaf(r2, v2.z, az); aw = fmaf(r2, v2.w, aw);
        ax = fmaf(r3, v3.x, ax); ay = fmaf(r3, v3.y, ay); az = fmaf(r3, v3.z, az); aw = fmaf(r3, v3.w, aw);
    }
    for (; i + 4 < e; i += 8) {
        int c0 = col[i], c1 = col[i + 4];
        float4 v0 = x4[c0 * 16 + li];
        float4 v1 = x4[c1 * 16 + li];
        float r0 = rso[c0], r1 = rso[c1];
        ax = fmaf(r0, v0.x, ax); ay = fmaf(r0, v0.y, ay); az = fmaf(r0, v0.z, az); aw = fmaf(r0, v0.w, aw);
        ax = fmaf(r1, v1.x, ax); ay = fmaf(r1, v1.y, ay); az = fmaf(r1, v1.z, az); aw = fmaf(r1, v1.w, aw);
    }
    for (; i < e; i += 4) {
        int c = col[i];
        float4 v = x4[c * 16 + li];
        float r = rso[c];
        ax = fmaf(r, v.x, ax); ay = fmaf(r, v.y, ay); az = fmaf(r, v.z, az); aw = fmaf(r, v.w, aw);
    }
    ax += __shfl_xor(ax, 16, 64); ay += __shfl_xor(ay, 16, 64);
    az += __shfl_xor(az, 16, 64); aw += __shfl_xor(aw, 16, 64);
    ax += __shfl_xor(ax, 32, 64); ay += __shfl_xor(ay, 32, 64);
    az += __shfl_xor(az, 32, 64); aw += __shfl_xor(aw, 32, 64);
    if (lane < 16) {
        float4 o; o.x = ax; o.y = ay; o.z = az; o.w = aw;
        agg4[wv * 16 + li] = o;
    }
}

// ---------------- gather-sum aggregation (128-dim) ----------------
__global__ __launch_bounds__(256) void k_gather128(const float4* __restrict__ h4, const int* __restrict__ rowp,
                                                   const int* __restrict__ col, float4* __restrict__ agg4) {
    int wv = (blockIdx.x * 256 + threadIdx.x) >> 6;
    if (wv >= N_NODES) return;
    int lane = threadIdx.x & 63;
    int grp = lane >> 5, li = lane & 31;
    int s = rowp[wv], e = rowp[wv + 1];
    float ax = 0.f, ay = 0.f, az = 0.f, aw = 0.f;
    int i = s + grp;
    for (; i + 14 < e; i += 16) {
        int c0 = col[i],      c1 = col[i + 2],  c2 = col[i + 4],  c3 = col[i + 6];
        int c4 = col[i + 8],  c5 = col[i + 10], c6 = col[i + 12], c7 = col[i + 14];
        float4 v0 = h4[c0 * 32 + li];
        float4 v1 = h4[c1 * 32 + li];
        float4 v2 = h4[c2 * 32 + li];
        float4 v3 = h4[c3 * 32 + li];
        float4 v4 = h4[c4 * 32 + li];
        float4 v5 = h4[c5 * 32 + li];
        float4 v6 = h4[c6 * 32 + li];
        float4 v7 = h4[c7 * 32 + li];
        ax += (v0.x + v1.x) + (v2.x + v3.x) + ((v4.x + v5.x) + (v6.x + v7.x));
        ay += (v0.y + v1.y) + (v2.y + v3.y) + ((v4.y + v5.y) + (v6.y + v7.y));
        az += (v0.z + v1.z) + (v2.z + v3.z) + ((v4.z + v5.z) + (v6.z + v7.z));
        aw += (v0.w + v1.w) + (v2.w + v3.w) + ((v4.w + v5.w) + (v6.w + v7.w));
    }
    for (; i + 6 < e; i += 8) {
        int c0 = col[i], c1 = col[i + 2], c2 = col[i + 4], c3 = col[i + 6];
        float4 v0 = h4[c0 * 32 + li];
        float4 v1 = h4[c1 * 32 + li];
        float4 v2 = h4[c2 * 32 + li];
        float4 v3 = h4[c3 * 32 + li];
        ax += v0.x + v1.x + v2.x + v3.x;
        ay += v0.y + v1.y + v2.y + v3.y;
        az += v0.z + v1.z + v2.z + v3.z;
        aw += v0.w + v1.w + v2.w + v3.w;
    }
    for (; i < e; i += 2) {
        float4 v = h4[col[i] * 32 + li];
        ax += v.x; ay += v.y; az += v.z; aw += v.w;
    }
    ax += __shfl_xor(ax, 32, 64); ay += __shfl_xor(ay, 32, 64);
    az += __shfl_xor(az, 32, 64); aw += __shfl_xor(aw, 32, 64);
    if (lane < 32) {
        float4 o; o.x = ax; o.y = ay; o.z = az; o.w = aw;
        agg4[wv * 32 + li] = o;
    }
}

// ---------------- layer-1 matmul, 64-node tile ----------------
template <int K, bool SCALE_OUT>
__global__ __launch_bounds__(256) void k_mm(const float* __restrict__ A, const float* __restrict__ W,
                                            const float* __restrict__ bias, const float* __restrict__ rsi,
                                            const float* __restrict__ rso, float* __restrict__ out) {
    __shared__ float WL[32 * 128];
    __shared__ float aL[64][33];
    const int t = threadIdx.x;
    const int jq = t & 31;
    const int ns = t >> 5;
    const int n0 = blockIdx.x * 64;
    float acc[8][4] = {};
    for (int kc = 0; kc < K; kc += 32) {
        const float4* Wg = (const float4*)(W + kc * 128);
        float4* WL4 = (float4*)WL;
#pragma unroll
        for (int u = 0; u < 4; ++u) WL4[t + 256 * u] = Wg[t + 256 * u];
        {
            int r = t >> 2, q = t & 3;
            int node = n0 + r;
#pragma unroll
            for (int h = 0; h < 2; ++h) {
                int qq = q + h * 4;
                float4 v = make_float4(0.f, 0.f, 0.f, 0.f);
                if (node < N_NODES) v = *(const float4*)(A + (size_t)node * K + kc + qq * 4);
                aL[r][qq * 4 + 0] = v.x; aL[r][qq * 4 + 1] = v.y;
                aL[r][qq * 4 + 2] = v.z; aL[r][qq * 4 + 3] = v.w;
            }
        }
        __syncthreads();
#pragma unroll
        for (int k = 0; k < 32; ++k) {
            float4 wv = ((const float4*)WL)[k * 32 + jq];
#pragma unroll
            for (int i = 0; i < 8; ++i) {
                float av = aL[ns * 8 + i][k];
                acc[i][0] += av * wv.x; acc[i][1] += av * wv.y;
                acc[i][2] += av * wv.z; acc[i][3] += av * wv.w;
            }
        }
        __syncthreads();
    }
#pragma unroll
    for (int i = 0; i < 8; ++i) {
        int node = n0 + ns * 8 + i;
        if (node >= N_NODES) continue;
        float ri = rsi[node];
        float ro = SCALE_OUT ? rso[node] : 1.0f;
        float4 bj = ((const float4*)bias)[jq];
        float4 o;
        o.x = fmaxf(acc[i][0] * ri + bj.x, 0.f) * ro;
        o.y = fmaxf(acc[i][1] * ri + bj.y, 0.f) * ro;
        o.z = fmaxf(acc[i][2] * ri + bj.z, 0.f) * ro;
        o.w = fmaxf(acc[i][3] * ri + bj.w, 0.f) * ro;
        *(float4*)(out + node * HID + jq * 4) = o;
    }
}

// ---------------- layer-2 matmul + fused mean-pool partial sums ----------------
// Same 64-node tile; instead of writing h2, accumulate per-graph column sums into
// gsum[512][128] via LDS gpart (nodes are gid-sorted; a 64-node tile spans <=2 graphs
// in practice, 8 LDS slots + global-atomic fallback for safety).
__global__ __launch_bounds__(256) void k_mm2pool(const float* __restrict__ A, const float* __restrict__ W,
                                                 const float* __restrict__ bias, const float* __restrict__ rsi,
                                                 const int* __restrict__ gid, float* __restrict__ gsum) {
    __shared__ float WL[32 * 128];
    __shared__ float aL[64][33];
    __shared__ float gpart[8][128];
    const int t = threadIdx.x;
    const int jq = t & 31;
    const int ns = t >> 5;
    const int n0 = blockIdx.x * 64;
    for (int u = t; u < 8 * 128; u += 256) ((float*)gpart)[u] = 0.f;
    float acc[8][4] = {};
    for (int kc = 0; kc < HID; kc += 32) {
        const float4* Wg = (const float4*)(W + kc * 128);
        float4* WL4 = (float4*)WL;
#pragma unroll
        for (int u = 0; u < 4; ++u) WL4[t + 256 * u] = Wg[t + 256 * u];
        {
            int r = t >> 2, q = t & 3;
            int node = n0 + r;
#pragma unroll
            for (int h = 0; h < 2; ++h) {
                int qq = q + h * 4;
                float4 v = make_float4(0.f, 0.f, 0.f, 0.f);
                if (node < N_NODES) v = *(const float4*)(A + (size_t)node * HID + kc + qq * 4);
                aL[r][qq * 4 + 0] = v.x; aL[r][qq * 4 + 1] = v.y;
                aL[r][qq * 4 + 2] = v.z; aL[r][qq * 4 + 3] = v.w;
            }
        }
        __syncthreads();
#pragma unroll
        for (int k = 0; k < 32; ++k) {
            float4 wv = ((const float4*)WL)[k * 32 + jq];
#pragma unroll
            for (int i = 0; i < 8; ++i) {
                float av = aL[ns * 8 + i][k];
                acc[i][0] += av * wv.x; acc[i][1] += av * wv.y;
                acc[i][2] += av * wv.z; acc[i][3] += av * wv.w;
            }
        }
        __syncthreads();
    }
    // epilogue: relu(acc*rsi + b), segment-sum by graph id, LDS partial, global atomic
    const int g0 = gid[n0];
    float4 bj = ((const float4*)bias)[jq];
    int curslot = -9;
    float p0 = 0.f, p1 = 0.f, p2 = 0.f, p3 = 0.f;
#pragma unroll
    for (int i = 0; i < 8; ++i) {
        int node = n0 + ns * 8 + i;
        if (node >= N_NODES) break;
        float ri = rsi[node];
        float ox = fmaxf(acc[i][0] * ri + bj.x, 0.f);
        float oy = fmaxf(acc[i][1] * ri + bj.y, 0.f);
        float oz = fmaxf(acc[i][2] * ri + bj.z, 0.f);
        float ow = fmaxf(acc[i][3] * ri + bj.w, 0.f);
        int slot = gid[node] - g0;
        if (slot != curslot) {
            if (curslot >= 0) {
                if (curslot < 8) {
                    atomicAdd(&gpart[curslot][jq * 4 + 0], p0);
                    atomicAdd(&gpart[curslot][jq * 4 + 1], p1);
                    atomicAdd(&gpart[curslot][jq * 4 + 2], p2);
                    atomicAdd(&gpart[curslot][jq * 4 + 3], p3);
                } else {
                    atomicAdd(&gsum[(g0 + curslot) * HID + jq * 4 + 0], p0);
                    atomicAdd(&gsum[(g0 + curslot) * HID + jq * 4 + 1], p1);
                    atomicAdd(&gsum[(g0 + curslot) * HID + jq * 4 + 2], p2);
                    atomicAdd(&gsum[(g0 + curslot) * HID + jq * 4 + 3], p3);
                }
            }
            curslot = slot; p0 = ox; p1 = oy; p2 = oz; p3 = ow;
        } else {
            p0 += ox; p1 += oy; p2 += oz; p3 += ow;
        }
    }
    if (curslot >= 0) {
        if (curslot < 8) {
            atomicAdd(&gpart[curslot][jq * 4 + 0], p0);
            atomicAdd(&gpart[curslot][jq * 4 + 1], p1);
            atomicAdd(&gpart[curslot][jq * 4 + 2], p2);
            atomicAdd(&gpart[curslot][jq * 4 + 3], p3);
        } else {
            atomicAdd(&gsum[(g0 + curslot) * HID + jq * 4 + 0], p0);
            atomicAdd(&gsum[(g0 + curslot) * HID + jq * 4 + 1], p1);
            atomicAdd(&gsum[(g0 + curslot) * HID + jq * 4 + 2], p2);
            atomicAdd(&gsum[(g0 + curslot) * HID + jq * 4 + 3], p3);
        }
    }
    __syncthreads();
    for (int u = t; u < 8 * 128; u += 256) {
        int slot = u >> 7, c = u & 127;
        float v = gpart[slot][c];
        if (v != 0.f) {
            int g = g0 + slot;
            if (g < N_GRAPHS) atomicAdd(&gsum[g * HID + c], v);
        }
    }
}

// ---------------- head: mean + 3-layer MLP per graph ----------------
__global__ __launch_bounds__(128) void k_head(const float* __restrict__ gsum, const int* __restrict__ gstart,
                                              const float* __restrict__ Wc1, const float* __restrict__ bc1,
                                              const float* __restrict__ Wc2, const float* __restrict__ bc2,
                                              const float* __restrict__ Wc3, const float* __restrict__ bc3,
                                              float* __restrict__ out) {
    int g = blockIdx.x, t = threadIdx.x;
    int s = gstart[g], e = gstart[g + 1];
    float cnt = fmaxf((float)(e - s), 1.0f);
    __shared__ float buf[HID];
    __shared__ float red[2];
    buf[t] = gsum[g * HID + t] / cnt;
    __syncthreads();
    float a = bc1[t];
#pragma unroll 8
    for (int k = 0; k < HID; ++k) a += buf[k] * Wc1[k * HID + t];
    a = fmaxf(a, 0.f);
    __syncthreads();
    buf[t] = a;
    __syncthreads();
    float b = bc2[t];
#pragma unroll 8
    for (int k = 0; k < HID; ++k) b += buf[k] * Wc2[k * HID + t];
    b = fmaxf(b, 0.f);
    float p = b * Wc3[t];
    for (int off = 32; off > 0; off >>= 1) p += __shfl_down(p, off, 64);
    if ((t & 63) == 0) red[t >> 6] = p;
    __syncthreads();
    if (t == 0) out[g] = red[0] + red[1] + bc3[0];
}

extern "C" void kernel_launch(void* const* d_in, const int* in_sizes, int n_in,
                              void* d_out, int out_size, void* d_ws, size_t ws_size,
                              hipStream_t stream) {
    const float* x   = (const float*)d_in[0];
    const int* esrc  = (const int*)d_in[1];
    const int* edst  = (const int*)d_in[2];
    const int* gid   = (const int*)d_in[3];
    const float* W1  = (const float*)d_in[4];
    const float* b1  = (const float*)d_in[5];
    const float* W2  = (const float*)d_in[6];
    const float* b2  = (const float*)d_in[7];
    const float* Wc1 = (const float*)d_in[8];
    const float* bc1 = (const float*)d_in[9];
    const float* Wc2 = (const float*)d_in[10];
    const float* bc2 = (const float*)d_in[11];
    const float* Wc3 = (const float*)d_in[12];
    const float* bc3 = (const float*)d_in[13];
    float* out = (float*)d_out;

    char* w = (char*)d_ws;
    size_t off = 0;
    auto alloc = [&](size_t bytes) -> char* {
        char* p = w + off;
        off += (bytes + 255) & ~(size_t)255;
        return p;
    };
    int* dcnt   = (int*)alloc((size_t)2 * (NBUCK + 1) * 4);  // dcnt+scnt contiguous (one memset)
    int* scnt   = dcnt + (NBUCK + 1);
    int* dbase  = (int*)alloc((size_t)(NBUCK + 1) * 4);
    int* sbase  = (int*)alloc((size_t)(NBUCK + 1) * 4);
    int* dcur   = (int*)alloc((size_t)NBUCK * 4);
    int* scur   = (int*)alloc((size_t)NBUCK * 4);
    float* rso  = (float*)alloc((size_t)N_NODES * 4);
    float* rsi  = (float*)alloc((size_t)N_NODES * 4);
    int* rowp   = (int*)alloc((size_t)(N_NODES + 1) * 4);
    int* gstart = (int*)alloc((size_t)(N_GRAPHS + 1) * 4);
    int* col    = (int*)alloc((size_t)N_EDGES * 4);
    float* gsum = (float*)alloc((size_t)N_GRAPHS * HID * 4);  // 256 KB
    float* R1   = (float*)alloc((size_t)N_NODES * HID * 4);   // binnedD|binnedS | agg1 | agg2
    float* R2   = (float*)alloc((size_t)N_NODES * HID * 4);   // h1s
    int* binnedD = (int*)R1;                     // 6.4 MB (packed src|dstLocal)
    int* binnedS = (int*)R1 + (size_t)N_EDGES;   // 6.4 MB
    float* agg1 = R1;
    float* agg2 = R1;
    float* h1s  = R2;

    (void)in_sizes; (void)n_in; (void)out_size; (void)ws_size;

    hipMemsetAsync(dcnt, 0, (size_t)2 * (NBUCK + 1) * 4, stream);
    hipMemsetAsync(gsum, 0, (size_t)N_GRAPHS * HID * 4, stream);

    const int BB = (N_EDGES + 4095) / 4096;     // 391 edge blocks
    const int GB = (N_NODES * 64 + 255) / 256;  // one wave per node
    const int MB64 = (N_NODES + 63) / 64;       // 1563 matmul blocks

    k_bhist<<<BB, 256, 0, stream>>>(esrc, edst, dcnt, scnt);
    k_bscan3<<<3, 512, 0, stream>>>(dcnt, scnt, gid, dbase, sbase, dcur, scur, gstart);
    k_bin2<<<BB, 256, 0, stream>>>(esrc, edst, dcur, scur, binnedD, binnedS);
    k_prep2<<<2 * NBUCK, 256, 0, stream>>>(dbase, sbase, binnedD, binnedS, rowp, rsi, rso, col);
    k_gather64<<<GB, 256, 0, stream>>>((const float4*)x, rso, rowp, col, (float4*)agg1);
    k_mm<IN_DIM, true><<<MB64, 256, 0, stream>>>(agg1, W1, b1, rsi, rso, h1s);
    k_gather128<<<GB, 256, 0, stream>>>((const float4*)h1s, rowp, col, (float4*)agg2);
    k_mm2pool<<<MB64, 256, 0, stream>>>(agg2, W2, b2, rsi, gid, gsum);
    k_head<<<N_GRAPHS, 128, 0, stream>>>(gsum, gstart, Wc1, bc1, Wc2, bc2, Wc3, bc3, out);
}

// Round 8
// 338.620 us; speedup vs baseline: 1.8579x; 1.0338x over previous
//
#include <hip/hip_runtime.h>

#define N_NODES 100000
#define N_EDGES 1600000
#define IN_DIM 64
#define HID 128
#define N_GRAPHS 512
#define NBUCK 391    // ceil(100000/256) buckets of 256 nodes

// ---------------- pass A: per-block LDS histogram of src/dst buckets ----------------
__global__ __launch_bounds__(256) void k_bhist(const int* __restrict__ src, const int* __restrict__ dst,
                                               int* __restrict__ dcnt, int* __restrict__ scnt) {
    __shared__ int hd[NBUCK];
    __shared__ int hs[NBUCK];
    const int t = threadIdx.x;
    const int e0 = blockIdx.x * 4096 + t * 16;
    for (int i = t; i < NBUCK; i += 256) { hd[i] = 0; hs[i] = 0; }
    __syncthreads();
    if (e0 < N_EDGES) {
        const int4* d4 = (const int4*)(dst + e0);
        const int4* s4 = (const int4*)(src + e0);
#pragma unroll
        for (int u = 0; u < 4; ++u) {
            int4 d = d4[u], s = s4[u];
            atomicAdd(&hd[d.x >> 8], 1); atomicAdd(&hd[d.y >> 8], 1);
            atomicAdd(&hd[d.z >> 8], 1); atomicAdd(&hd[d.w >> 8], 1);
            atomicAdd(&hs[s.x >> 8], 1); atomicAdd(&hs[s.y >> 8], 1);
            atomicAdd(&hs[s.z >> 8], 1); atomicAdd(&hs[s.w >> 8], 1);
        }
    }
    __syncthreads();
    for (int i = t; i < NBUCK; i += 256) {
        if (hd[i]) atomicAdd(&dcnt[i], hd[i]);
        if (hs[i]) atomicAdd(&scnt[i], hs[i]);
    }
}

// ---------------- scans (blocks 0,1) + per-graph bounds (block 2) ----------------
__global__ __launch_bounds__(512) void k_bscan3(const int* __restrict__ dcnt, const int* __restrict__ scnt,
                                                const int* __restrict__ gid,
                                                int* __restrict__ dbase, int* __restrict__ sbase,
                                                int* __restrict__ dcur, int* __restrict__ scur,
                                                int* __restrict__ gstart) {
    const int t = threadIdx.x;
    if (blockIdx.x == 2) {
        for (int g = t; g <= N_GRAPHS; g += 512) {
            int lo = 0, hi = N_NODES;
            while (lo < hi) {
                int mid = (lo + hi) >> 1;
                if (gid[mid] < g) lo = mid + 1; else hi = mid;
            }
            gstart[g] = lo;
        }
        return;
    }
    __shared__ int l[512];
    const int* cntp = (blockIdx.x == 0) ? dcnt : scnt;
    int* basep = (blockIdx.x == 0) ? dbase : sbase;
    int* curp  = (blockIdx.x == 0) ? dcur  : scur;
    int v = (t < NBUCK) ? cntp[t] : 0;
    l[t] = v;
    __syncthreads();
    for (int off = 1; off < 512; off <<= 1) {
        int x = (t >= off) ? l[t - off] : 0;
        __syncthreads();
        l[t] += x;
        __syncthreads();
    }
    if (t < NBUCK) {
        int excl = l[t] - v;
        basep[t] = excl; curp[t] = excl;
    }
    if (t == NBUCK - 1) basep[NBUCK] = l[t];
}

// ---------------- pass B: bin by dst bucket (packed src|dstLocal) AND by src bucket ----------------
__global__ __launch_bounds__(256) void k_bin2(const int* __restrict__ src, const int* __restrict__ dst,
                                              int* __restrict__ dcur, int* __restrict__ scur,
                                              int* __restrict__ binnedD, int* __restrict__ binnedS) {
    __shared__ int hd[NBUCK];
    __shared__ int bd[NBUCK];
    __shared__ int hs[NBUCK];
    __shared__ int bs[NBUCK];
    const int t = threadIdx.x;
    const int e0 = blockIdx.x * 4096 + t * 16;
    for (int i = t; i < NBUCK; i += 256) { hd[i] = 0; hs[i] = 0; }
    __syncthreads();
    if (e0 < N_EDGES) {
        const int4* d4 = (const int4*)(dst + e0);
        const int4* s4 = (const int4*)(src + e0);
#pragma unroll
        for (int u = 0; u < 4; ++u) {
            int4 d = d4[u], s = s4[u];
            atomicAdd(&hd[d.x >> 8], 1); atomicAdd(&hd[d.y >> 8], 1);
            atomicAdd(&hd[d.z >> 8], 1); atomicAdd(&hd[d.w >> 8], 1);
            atomicAdd(&hs[s.x >> 8], 1); atomicAdd(&hs[s.y >> 8], 1);
            atomicAdd(&hs[s.z >> 8], 1); atomicAdd(&hs[s.w >> 8], 1);
        }
    }
    __syncthreads();
    for (int i = t; i < NBUCK; i += 256) {
        int c = hd[i];
        bd[i] = c ? atomicAdd(&dcur[i], c) : 0;
        hd[i] = 0;
        c = hs[i];
        bs[i] = c ? atomicAdd(&scur[i], c) : 0;
        hs[i] = 0;
    }
    __syncthreads();
    if (e0 < N_EDGES) {
        const int4* d4 = (const int4*)(dst + e0);
        const int4* s4 = (const int4*)(src + e0);
#pragma unroll
        for (int u = 0; u < 4; ++u) {
            int4 d = d4[u];
            int4 s = s4[u];
            int bk, r;
            bk = d.x >> 8; r = atomicAdd(&hd[bk], 1); binnedD[bd[bk] + r] = s.x | ((d.x & 255) << 17);
            bk = d.y >> 8; r = atomicAdd(&hd[bk], 1); binnedD[bd[bk] + r] = s.y | ((d.y & 255) << 17);
            bk = d.z >> 8; r = atomicAdd(&hd[bk], 1); binnedD[bd[bk] + r] = s.z | ((d.z & 255) << 17);
            bk = d.w >> 8; r = atomicAdd(&hd[bk], 1); binnedD[bd[bk] + r] = s.w | ((d.w & 255) << 17);
            bk = s.x >> 8; r = atomicAdd(&hs[bk], 1); binnedS[bs[bk] + r] = s.x;
            bk = s.y >> 8; r = atomicAdd(&hs[bk], 1); binnedS[bs[bk] + r] = s.y;
            bk = s.z >> 8; r = atomicAdd(&hs[bk], 1); binnedS[bs[bk] + r] = s.z;
            bk = s.w >> 8; r = atomicAdd(&hs[bk], 1); binnedS[bs[bk] + r] = s.w;
        }
    }
}

// ---------------- pass C: CSR build (blocks 0..NBUCK-1) + out-degree rso (blocks NBUCK..) ----------------
__global__ __launch_bounds__(256) void k_prep2(const int* __restrict__ dbase, const int* __restrict__ sbase,
                                               const int* __restrict__ binnedD, const int* __restrict__ binnedS,
                                               int* __restrict__ rowp, float* __restrict__ rsi,
                                               float* __restrict__ rso, int* __restrict__ col) {
    const int t = threadIdx.x;
    if (blockIdx.x < NBUCK) {
        const int b = blockIdx.x;
        const int n0 = b * 256;
        __shared__ int cnt[256];
        __shared__ int scn[256];
        __shared__ int cur[256];
        __shared__ int sb[2];
        if (t < 2) sb[t] = dbase[b + t];
        cnt[t] = 0;
        __syncthreads();
        const int s = sb[0], e = sb[1];
        for (int i = s + t; i < e; i += 256) atomicAdd(&cnt[binnedD[i] >> 17], 1);
        __syncthreads();
        const int c = cnt[t];
        scn[t] = c;
        __syncthreads();
        for (int off = 1; off < 256; off <<= 1) {
            int v = (t >= off) ? scn[t - off] : 0;
            __syncthreads();
            scn[t] += v;
            __syncthreads();
        }
        const int excl = scn[t] - c;
        cur[t] = excl;
        if (n0 + t < N_NODES) {
            rowp[n0 + t] = s + excl;
            rsi[n0 + t] = 1.0f / sqrtf(fmaxf((float)c, 1.0f));
        }
        if (b == NBUCK - 1 && t == 0) rowp[N_NODES] = e;
        __syncthreads();
        for (int i = s + t; i < e; i += 256) {
            int p = binnedD[i];
            int r = atomicAdd(&cur[p >> 17], 1);
            col[s + r] = p & 0x1FFFF;
        }
    } else {
        const int b = blockIdx.x - NBUCK;
        const int n0 = b * 256;
        __shared__ int cnt2[256];
        __shared__ int sb2[2];
        if (t < 2) sb2[t] = sbase[b + t];
        cnt2[t] = 0;
        __syncthreads();
        const int s = sb2[0], e = sb2[1];
        for (int i = s + t; i < e; i += 256) atomicAdd(&cnt2[binnedS[i] - n0], 1);
        __syncthreads();
        if (n0 + t < N_NODES) rso[n0 + t] = 1.0f / sqrtf(fmaxf((float)cnt2[t], 1.0f));
    }
}

// ---------------- gather-sum aggregation (64-dim), rso scale fused ----------------
__global__ __launch_bounds__(256) void k_gather64(const float4* __restrict__ x4, const float* __restrict__ rso,
                                                  const int* __restrict__ rowp, const int* __restrict__ col,
                                                  float4* __restrict__ agg4) {
    int wv = (blockIdx.x * 256 + threadIdx.x) >> 6;
    if (wv >= N_NODES) return;
    int lane = threadIdx.x & 63;
    int grp = lane >> 4, li = lane & 15;
    int s = rowp[wv], e = rowp[wv + 1];
    float ax = 0.f, ay = 0.f, az = 0.f, aw = 0.f;
    int i = s + grp;
    for (; i + 12 < e; i += 16) {
        int c0 = col[i], c1 = col[i + 4], c2 = col[i + 8], c3 = col[i + 12];
        float4 v0 = x4[c0 * 16 + li];
        float4 v1 = x4[c1 * 16 + li];
        float4 v2 = x4[c2 * 16 + li];
        float4 v3 = x4[c3 * 16 + li];
        float r0 = rso[c0], r1 = rso[c1], r2 = rso[c2], r3 = rso[c3];
        ax = fmaf(r0, v0.x, ax); ay = fmaf(r0, v0.y, ay); az = fmaf(r0, v0.z, az); aw = fmaf(r0, v0.w, aw);
        ax = fmaf(r1, v1.x, ax); ay = fmaf(r1, v1.y, ay); az = fmaf(r1, v1.z, az); aw = fmaf(r1, v1.w, aw);
        ax = fmaf(r2, v2.x, ax); ay = fmaf(r2, v2.y, ay); az = fmaf(r2, v2.z, az); aw = fmaf(r2, v2.w, aw);
        ax = fmaf(r3, v3.x, ax); ay = fmaf(r3, v3.y, ay); az = fmaf(r3, v3.z, az); aw = fmaf(r3, v3.w, aw);
    }
    for (; i + 4 < e; i += 8) {
        int c0 = col[i], c1 = col[i + 4];
        float4 v0 = x4[c0 * 16 + li];
        float4 v1 = x4[c1 * 16 + li];
        float r0 = rso[c0], r1 = rso[c1];
        ax = fmaf(r0, v0.x, ax); ay = fmaf(r0, v0.y, ay); az = fmaf(r0, v0.z, az); aw = fmaf(r0, v0.w, aw);
        ax = fmaf(r1, v1.x, ax); ay = fmaf(r1, v1.y, ay); az = fmaf(r1, v1.z, az); aw = fmaf(r1, v1.w, aw);
    }
    for (; i < e; i += 4) {
        int c = col[i];
        float4 v = x4[c * 16 + li];
        float r = rso[c];
        ax = fmaf(r, v.x, ax); ay = fmaf(r, v.y, ay); az = fmaf(r, v.z, az); aw = fmaf(r, v.w, aw);
    }
    ax += __shfl_xor(ax, 16, 64); ay += __shfl_xor(ay, 16, 64);
    az += __shfl_xor(az, 16, 64); aw += __shfl_xor(aw, 16, 64);
    ax += __shfl_xor(ax, 32, 64); ay += __shfl_xor(ay, 32, 64);
    az += __shfl_xor(az, 32, 64); aw += __shfl_xor(aw, 32, 64);
    if (lane < 16) {
        float4 o; o.x = ax; o.y = ay; o.z = az; o.w = aw;
        agg4[wv * 16 + li] = o;
    }
}

// ---------------- layer-1 matmul, 64-node tile ----------------
template <int K, bool SCALE_OUT>
__global__ __launch_bounds__(256) void k_mm(const float* __restrict__ A, const float* __restrict__ W,
                                            const float* __restrict__ bias, const float* __restrict__ rsi,
                                            const float* __restrict__ rso, float* __restrict__ out) {
    __shared__ float WL[32 * 128];
    __shared__ float aL[64][33];
    const int t = threadIdx.x;
    const int jq = t & 31;
    const int ns = t >> 5;
    const int n0 = blockIdx.x * 64;
    float acc[8][4] = {};
    for (int kc = 0; kc < K; kc += 32) {
        const float4* Wg = (const float4*)(W + kc * 128);
        float4* WL4 = (float4*)WL;
#pragma unroll
        for (int u = 0; u < 4; ++u) WL4[t + 256 * u] = Wg[t + 256 * u];
        {
            int r = t >> 2, q = t & 3;
            int node = n0 + r;
#pragma unroll
            for (int h = 0; h < 2; ++h) {
                int qq = q + h * 4;
                float4 v = make_float4(0.f, 0.f, 0.f, 0.f);
                if (node < N_NODES) v = *(const float4*)(A + (size_t)node * K + kc + qq * 4);
                aL[r][qq * 4 + 0] = v.x; aL[r][qq * 4 + 1] = v.y;
                aL[r][qq * 4 + 2] = v.z; aL[r][qq * 4 + 3] = v.w;
            }
        }
        __syncthreads();
#pragma unroll
        for (int k = 0; k < 32; ++k) {
            float4 wv = ((const float4*)WL)[k * 32 + jq];
#pragma unroll
            for (int i = 0; i < 8; ++i) {
                float av = aL[ns * 8 + i][k];
                acc[i][0] += av * wv.x; acc[i][1] += av * wv.y;
                acc[i][2] += av * wv.z; acc[i][3] += av * wv.w;
            }
        }
        __syncthreads();
    }
#pragma unroll
    for (int i = 0; i < 8; ++i) {
        int node = n0 + ns * 8 + i;
        if (node >= N_NODES) continue;
        float ri = rsi[node];
        float ro = SCALE_OUT ? rso[node] : 1.0f;
        float4 bj = ((const float4*)bias)[jq];
        float4 o;
        o.x = fmaxf(acc[i][0] * ri + bj.x, 0.f) * ro;
        o.y = fmaxf(acc[i][1] * ri + bj.y, 0.f) * ro;
        o.z = fmaxf(acc[i][2] * ri + bj.z, 0.f) * ro;
        o.w = fmaxf(acc[i][3] * ri + bj.w, 0.f) * ro;
        *(float4*)(out + node * HID + jq * 4) = o;
    }
}

// ---------------- fused layer-2: gather(128) -> LDS -> matmul W2 -> pooled partial sums ----------------
// 256 threads = 32 dst nodes (N_NODES = 3125*32 exactly). Phase 1: 4 waves gather
// 8 nodes each into agg[32][128]. Phase 2: tiled matmul from LDS; epilogue does the
// relu + segment-sum by graph into gsum (no h2/agg2 ever materialized).
// __launch_bounds__(256,4): force VGPR<=128 -> 4 blocks/CU (LDS 36KB) = 16 waves/CU.
__global__ __launch_bounds__(256, 4) void k_g128p(const float4* __restrict__ h4, const int* __restrict__ rowp,
                                                  const int* __restrict__ col, const float* __restrict__ W,
                                                  const float* __restrict__ bias, const float* __restrict__ rsi,
                                                  const int* __restrict__ gid, float* __restrict__ gsum) {
    __shared__ float agg[32][HID];   // 16 KB
    __shared__ float WL[32 * 128];   // 16 KB
    __shared__ float gpart[8][128];  // 4 KB
    const int t = threadIdx.x;
    const int wid = t >> 6, lane = t & 63;
    const int n0 = blockIdx.x * 32;
    for (int u = t; u < 8 * 128; u += 256) ((float*)gpart)[u] = 0.f;

    // ---- phase 1: gather 8 nodes per wave (r4 pattern: 2 groups x 4-unroll) ----
    const int grp = lane >> 5, li = lane & 31;
#pragma unroll 1
    for (int it = 0; it < 8; ++it) {
        const int node = n0 + wid * 8 + it;
        const int s = rowp[node], e = rowp[node + 1];
        float ax = 0.f, ay = 0.f, az = 0.f, aw = 0.f;
        int i = s + grp;
        for (; i + 6 < e; i += 8) {
            int c0 = col[i], c1 = col[i + 2], c2 = col[i + 4], c3 = col[i + 6];
            float4 v0 = h4[c0 * 32 + li];
            float4 v1 = h4[c1 * 32 + li];
            float4 v2 = h4[c2 * 32 + li];
            float4 v3 = h4[c3 * 32 + li];
            ax += v0.x + v1.x + v2.x + v3.x;
            ay += v0.y + v1.y + v2.y + v3.y;
            az += v0.z + v1.z + v2.z + v3.z;
            aw += v0.w + v1.w + v2.w + v3.w;
        }
        for (; i < e; i += 2) {
            float4 v = h4[col[i] * 32 + li];
            ax += v.x; ay += v.y; az += v.z; aw += v.w;
        }
        ax += __shfl_xor(ax, 32, 64); ay += __shfl_xor(ay, 32, 64);
        az += __shfl_xor(az, 32, 64); aw += __shfl_xor(aw, 32, 64);
        if (lane < 32) {
            float4 o; o.x = ax; o.y = ay; o.z = az; o.w = aw;
            ((float4*)agg[node - n0])[li] = o;
        }
    }
    __syncthreads();

    // ---- phase 2: matmul from LDS agg ----
    const int jq = t & 31;   // columns jq*4..jq*4+3
    const int ns = t >> 5;   // nodes ns*4..ns*4+3
    float acc[4][4] = {};
    for (int kc = 0; kc < HID; kc += 32) {
        const float4* Wg = (const float4*)(W + kc * 128);
        float4* WL4 = (float4*)WL;
#pragma unroll
        for (int u = 0; u < 4; ++u) WL4[t + 256 * u] = Wg[t + 256 * u];
        __syncthreads();
#pragma unroll
        for (int k = 0; k < 32; ++k) {
            float4 wv = ((const float4*)WL)[k * 32 + jq];
#pragma unroll
            for (int i = 0; i < 4; ++i) {
                float av = agg[ns * 4 + i][kc + k];
                acc[i][0] += av * wv.x; acc[i][1] += av * wv.y;
                acc[i][2] += av * wv.z; acc[i][3] += av * wv.w;
            }
        }
        __syncthreads();
    }

    // ---- epilogue: relu + segment-sum by graph into gpart/gsum ----
    const int g0 = gid[n0];
    float4 bj = ((const float4*)bias)[jq];
    int curslot = -9;
    float p0 = 0.f, p1 = 0.f, p2 = 0.f, p3 = 0.f;
#pragma unroll
    for (int i = 0; i < 4; ++i) {
        int node = n0 + ns * 4 + i;
        float ri = rsi[node];
        float ox = fmaxf(acc[i][0] * ri + bj.x, 0.f);
        float oy = fmaxf(acc[i][1] * ri + bj.y, 0.f);
        float oz = fmaxf(acc[i][2] * ri + bj.z, 0.f);
        float ow = fmaxf(acc[i][3] * ri + bj.w, 0.f);
        int slot = gid[node] - g0;
        if (slot != curslot) {
            if (curslot >= 0) {
                if (curslot < 8) {
                    atomicAdd(&gpart[curslot][jq * 4 + 0], p0);
                    atomicAdd(&gpart[curslot][jq * 4 + 1], p1);
                    atomicAdd(&gpart[curslot][jq * 4 + 2], p2);
                    atomicAdd(&gpart[curslot][jq * 4 + 3], p3);
                } else {
                    atomicAdd(&gsum[(g0 + curslot) * HID + jq * 4 + 0], p0);
                    atomicAdd(&gsum[(g0 + curslot) * HID + jq * 4 + 1], p1);
                    atomicAdd(&gsum[(g0 + curslot) * HID + jq * 4 + 2], p2);
                    atomicAdd(&gsum[(g0 + curslot) * HID + jq * 4 + 3], p3);
                }
            }
            curslot = slot; p0 = ox; p1 = oy; p2 = oz; p3 = ow;
        } else {
            p0 += ox; p1 += oy; p2 += oz; p3 += ow;
        }
    }
    if (curslot >= 0) {
        if (curslot < 8) {
            atomicAdd(&gpart[curslot][jq * 4 + 0], p0);
            atomicAdd(&gpart[curslot][jq * 4 + 1], p1);
            atomicAdd(&gpart[curslot][jq * 4 + 2], p2);
            atomicAdd(&gpart[curslot][jq * 4 + 3], p3);
        } else {
            atomicAdd(&gsum[(g0 + curslot) * HID + jq * 4 + 0], p0);
            atomicAdd(&gsum[(g0 + curslot) * HID + jq * 4 + 1], p1);
            atomicAdd(&gsum[(g0 + curslot) * HID + jq * 4 + 2], p2);
            atomicAdd(&gsum[(g0 + curslot) * HID + jq * 4 + 3], p3);
        }
    }
    __syncthreads();
    for (int u = t; u < 8 * 128; u += 256) {
        int slot = u >> 7, c = u & 127;
        float v = gpart[slot][c];
        if (v != 0.f) {
            int g = g0 + slot;
            if (g < N_GRAPHS) atomicAdd(&gsum[g * HID + c], v);
        }
    }
}

// ---------------- head: mean + 3-layer MLP per graph ----------------
__global__ __launch_bounds__(128) void k_head(const float* __restrict__ gsum, const int* __restrict__ gstart,
                                              const float* __restrict__ Wc1, const float* __restrict__ bc1,
                                              const float* __restrict__ Wc2, const float* __restrict__ bc2,
                                              const float* __restrict__ Wc3, const float* __restrict__ bc3,
                                              float* __restrict__ out) {
    int g = blockIdx.x, t = threadIdx.x;
    int s = gstart[g], e = gstart[g + 1];
    float cnt = fmaxf((float)(e - s), 1.0f);
    __shared__ float buf[HID];
    __shared__ float red[2];
    buf[t] = gsum[g * HID + t] / cnt;
    __syncthreads();
    float a = bc1[t];
#pragma unroll 8
    for (int k = 0; k < HID; ++k) a += buf[k] * Wc1[k * HID + t];
    a = fmaxf(a, 0.f);
    __syncthreads();
    buf[t] = a;
    __syncthreads();
    float b = bc2[t];
#pragma unroll 8
    for (int k = 0; k < HID; ++k) b += buf[k] * Wc2[k * HID + t];
    b = fmaxf(b, 0.f);
    float p = b * Wc3[t];
    for (int off = 32; off > 0; off >>= 1) p += __shfl_down(p, off, 64);
    if ((t & 63) == 0) red[t >> 6] = p;
    __syncthreads();
    if (t == 0) out[g] = red[0] + red[1] + bc3[0];
}

extern "C" void kernel_launch(void* const* d_in, const int* in_sizes, int n_in,
                              void* d_out, int out_size, void* d_ws, size_t ws_size,
                              hipStream_t stream) {
    const float* x   = (const float*)d_in[0];
    const int* esrc  = (const int*)d_in[1];
    const int* edst  = (const int*)d_in[2];
    const int* gid   = (const int*)d_in[3];
    const float* W1  = (const float*)d_in[4];
    const float* b1  = (const float*)d_in[5];
    const float* W2  = (const float*)d_in[6];
    const float* b2  = (const float*)d_in[7];
    const float* Wc1 = (const float*)d_in[8];
    const float* bc1 = (const float*)d_in[9];
    const float* Wc2 = (const float*)d_in[10];
    const float* bc2 = (const float*)d_in[11];
    const float* Wc3 = (const float*)d_in[12];
    const float* bc3 = (const float*)d_in[13];
    float* out = (float*)d_out;

    char* w = (char*)d_ws;
    size_t off = 0;
    auto alloc = [&](size_t bytes) -> char* {
        char* p = w + off;
        off += (bytes + 255) & ~(size_t)255;
        return p;
    };
    int* dcnt   = (int*)alloc((size_t)2 * (NBUCK + 1) * 4);  // dcnt+scnt contiguous (one memset)
    int* scnt   = dcnt + (NBUCK + 1);
    int* dbase  = (int*)alloc((size_t)(NBUCK + 1) * 4);
    int* sbase  = (int*)alloc((size_t)(NBUCK + 1) * 4);
    int* dcur   = (int*)alloc((size_t)NBUCK * 4);
    int* scur   = (int*)alloc((size_t)NBUCK * 4);
    float* rso  = (float*)alloc((size_t)N_NODES * 4);
    float* rsi  = (float*)alloc((size_t)N_NODES * 4);
    int* rowp   = (int*)alloc((size_t)(N_NODES + 1) * 4);
    int* gstart = (int*)alloc((size_t)(N_GRAPHS + 1) * 4);
    int* col    = (int*)alloc((size_t)N_EDGES * 4);
    float* gsum = (float*)alloc((size_t)N_GRAPHS * HID * 4);  // 256 KB
    float* R1   = (float*)alloc((size_t)N_NODES * HID * 4);   // binnedD|binnedS | agg1
    float* R2   = (float*)alloc((size_t)N_NODES * HID * 4);   // h1s
    int* binnedD = (int*)R1;                     // 6.4 MB (packed src|dstLocal)
    int* binnedS = (int*)R1 + (size_t)N_EDGES;   // 6.4 MB
    float* agg1 = R1;
    float* h1s  = R2;

    (void)in_sizes; (void)n_in; (void)out_size; (void)ws_size;

    hipMemsetAsync(dcnt, 0, (size_t)2 * (NBUCK + 1) * 4, stream);
    hipMemsetAsync(gsum, 0, (size_t)N_GRAPHS * HID * 4, stream);

    const int BB = (N_EDGES + 4095) / 4096;     // 391 edge blocks
    const int GB = (N_NODES * 64 + 255) / 256;  // one wave per node
    const int MB64 = (N_NODES + 63) / 64;       // 1563 layer-1 matmul blocks
    const int FB32 = N_NODES / 32;              // 3125 fused layer-2 blocks (exact)

    k_bhist<<<BB, 256, 0, stream>>>(esrc, edst, dcnt, scnt);
    k_bscan3<<<3, 512, 0, stream>>>(dcnt, scnt, gid, dbase, sbase, dcur, scur, gstart);
    k_bin2<<<BB, 256, 0, stream>>>(esrc, edst, dcur, scur, binnedD, binnedS);
    k_prep2<<<2 * NBUCK, 256, 0, stream>>>(dbase, sbase, binnedD, binnedS, rowp, rsi, rso, col);
    k_gather64<<<GB, 256, 0, stream>>>((const float4*)x, rso, rowp, col, (float4*)agg1);
    k_mm<IN_DIM, true><<<MB64, 256, 0, stream>>>(agg1, W1, b1, rsi, rso, h1s);
    k_g128p<<<FB32, 256, 0, stream>>>((const float4*)h1s, rowp, col, W2, b2, rsi, gid, gsum);
    k_head<<<N_GRAPHS, 128, 0, stream>>>(gsum, gstart, Wc1, bc1, Wc2, bc2, Wc3, bc3, out);
}